// Round 1
// 1096.787 us; speedup vs baseline: 1.0229x; 1.0229x over previous
//
#include <hip/hip_runtime.h>
#include <hip/hip_bf16.h>
#include <stdint.h>

#define B_    2
#define T_    2048
#define EMB_  2048
#define NH_   16
#define NKV_  4
#define HD_   128
#define MLPD_ 8192
#define WIN_  1024
#define BT_   (B_ * T_)     // 4096 rows
#define QKVN_ 3072          // NH*HD + NKV*HD + NKV*HD

typedef __bf16 bf16;
typedef __bf16 bf16x8 __attribute__((ext_vector_type(8)));
typedef float  f32x4  __attribute__((ext_vector_type(4)));

__device__ __forceinline__ bf16 f2b(float f) {
  __hip_bfloat16 h = __float2bfloat16(f);
  return *reinterpret_cast<bf16*>(&h);
}
__device__ __forceinline__ float b2f(bf16 b) {
  __hip_bfloat16 h = *reinterpret_cast<__hip_bfloat16*>(&b);
  return __bfloat162float(h);
}

__device__ __forceinline__ void load_lds16(const void* g, void* l) {
  __builtin_amdgcn_global_load_lds(
      (const __attribute__((address_space(1))) void*)g,
      (__attribute__((address_space(3))) void*)l, 16, 0, 0);
}

// ---------- transpose f32 [R][C] -> bf16 [remap(C)][R] ----------
// remap(c) = (c&15) + ((c>>4)*rmul + radd)*16 ; (1,0) = identity.
// (2,0)/(2,1) interleave two matrices in 16-row blocks (gate/up fusion layout).
__global__ __launch_bounds__(256) void transpose_kernel(
    const float* __restrict__ in, bf16* __restrict__ out, int R, int C,
    int rmul, int radd)
{
  __shared__ float tile[32][33];
  const int tx = threadIdx.x, ty = threadIdx.y;  // blockDim (32,8)
  const int c0 = blockIdx.x * 32, r0 = blockIdx.y * 32;
  #pragma unroll
  for (int i = 0; i < 32; i += 8)
    tile[ty + i][tx] = in[(long)(r0 + ty + i) * C + c0 + tx];
  __syncthreads();
  #pragma unroll
  for (int i = 0; i < 32; i += 8) {
    const int oc = c0 + ty + i;
    const int orow = (oc & 15) + (((oc >> 4) * rmul + radd) << 4);
    out[(long)orow * R + r0 + tx] = f2b(tile[tx][ty + i]);
  }
}

// ---------- RMSNorm: f32 row -> bf16 row ----------
__global__ __launch_bounds__(256) void rmsnorm_kernel(
    const float* __restrict__ x, const float* __restrict__ scale,
    bf16* __restrict__ out)
{
  const long row = blockIdx.x;
  const float* xr = x + row * EMB_;
  bf16* orow = out + row * EMB_;
  const float4 v0 = ((const float4*)xr)[threadIdx.x];
  const float4 v1 = ((const float4*)xr)[threadIdx.x + 256];
  float ss = v0.x*v0.x + v0.y*v0.y + v0.z*v0.z + v0.w*v0.w
           + v1.x*v1.x + v1.y*v1.y + v1.z*v1.z + v1.w*v1.w;
  #pragma unroll
  for (int off = 32; off >= 1; off >>= 1) ss += __shfl_xor(ss, off, 64);
  __shared__ float red[4];
  if ((threadIdx.x & 63) == 0) red[threadIdx.x >> 6] = ss;
  __syncthreads();
  const float tot = red[0] + red[1] + red[2] + red[3];
  const float rs = rsqrtf(tot * (1.0f / EMB_) + 1e-6f);
  const float4 s0 = ((const float4*)scale)[threadIdx.x];
  const float4 s1 = ((const float4*)scale)[threadIdx.x + 256];
  const int c0 = threadIdx.x * 4;
  orow[c0 + 0]    = f2b(v0.x * rs * (1.0f + s0.x));
  orow[c0 + 1]    = f2b(v0.y * rs * (1.0f + s0.y));
  orow[c0 + 2]    = f2b(v0.z * rs * (1.0f + s0.z));
  orow[c0 + 3]    = f2b(v0.w * rs * (1.0f + s0.w));
  orow[c0 + 1024] = f2b(v1.x * rs * (1.0f + s1.x));
  orow[c0 + 1025] = f2b(v1.y * rs * (1.0f + s1.y));
  orow[c0 + 1026] = f2b(v1.z * rs * (1.0f + s1.z));
  orow[c0 + 1027] = f2b(v1.w * rs * (1.0f + s1.w));
}

// ---------- GEMM: C[M][N] = A[M][K] * Bt[N][K]^T, bf16 in, f32 acc ----------
// EPI 0: bf16 out.  EPI 1: f32 out = acc + res (res may alias out, same-elem RMW).
template <int EPI>
__global__ __launch_bounds__(256) void gemm_kernel(
    const bf16* __restrict__ A, const bf16* __restrict__ Bt,
    void* __restrict__ out, const float* __restrict__ res,
    int M, int N, int K)
{
  __shared__ __align__(16) bf16 As[128 * 32];
  __shared__ __align__(16) bf16 Bs[128 * 32];
  const int tid  = threadIdx.x;
  const int wave = tid >> 6, lane = tid & 63;
  const int bm = blockIdx.y << 7, bn = blockIdx.x << 7;
  const int wm = (wave & 1) << 6, wn = (wave >> 1) << 6;
  const int l16 = lane & 15, quad = lane >> 4;
  const int srow = lane >> 2, scol = (lane & 3) << 3;

  const bf16* Ap = A  + (long)(bm + wave * 32 + srow) * K + scol;
  const bf16* Bp = Bt + (long)(bn + wave * 32 + srow) * K + scol;
  char* ldsA = (char*)As + wave * 2048;
  char* ldsB = (char*)Bs + wave * 2048;

  f32x4 acc[4][4] = {};

  for (int k0 = 0; k0 < K; k0 += 32) {
    __syncthreads();
    #pragma unroll
    for (int j = 0; j < 2; ++j) {
      load_lds16(Ap + (long)j * 16 * K + k0, ldsA + j * 1024);
      load_lds16(Bp + (long)j * 16 * K + k0, ldsB + j * 1024);
    }
    __syncthreads();
    bf16x8 af[4], bfr[4];
    #pragma unroll
    for (int i = 0; i < 4; ++i) {
      af[i]  = *(const bf16x8*)&As[(wm + i * 16 + l16) * 32 + quad * 8];
      bfr[i] = *(const bf16x8*)&Bs[(wn + i * 16 + l16) * 32 + quad * 8];
    }
    #pragma unroll
    for (int mb = 0; mb < 4; ++mb)
      #pragma unroll
      for (int nb = 0; nb < 4; ++nb)
        acc[mb][nb] = __builtin_amdgcn_mfma_f32_16x16x32_bf16(af[mb], bfr[nb], acc[mb][nb], 0, 0, 0);
  }

  const int crow = bm + wm + (quad << 2);
  const int ccol = bn + wn + l16;
  #pragma unroll
  for (int mb = 0; mb < 4; ++mb)
    #pragma unroll
    for (int nb = 0; nb < 4; ++nb)
      #pragma unroll
      for (int r = 0; r < 4; ++r) {
        const long idx = (long)(crow + mb * 16 + r) * N + (ccol + nb * 16);
        const float v = acc[mb][nb][r];
        if (EPI == 0) {
          ((bf16*)out)[idx] = f2b(v);
        } else {
          ((float*)out)[idx] = v + res[idx];
        }
      }
}

// ================== Fused gate+up 256x256 8-phase GEMM ==================
// A [M][K] bf16 (rmsnorm out); Bc [Ncat=16384][K] bf16 with gate/up weights
// interleaved in 16-row blocks (even block = gate col block, odd = up).
// out[m][n] = silu(g)*u  for n in [0, Ncat/2), bf16.
//
// Structure (256sq 8-phase template, plain HIP):
//  - BM=BN=256, BK=64, 8 waves (2M x 4N), per-wave 128x64 output.
//  - LDS 128 KiB: 2 dbuf x {A half0, A half1, B half0, B half1} x 16 KiB.
//  - XOR swizzle off^=((row&7)<<4): applied via pre-swizzled global source
//    (gload_lds dest linear) + same XOR folded into ds_read offsets -> b128
//    fragment reads spread 8 lanes/16B-slot (wave64 floor, conflict-free).
//  - 8 phases / 2 K-tiles. Stage bursts at p0 (tile t+1 -> buf1) and p4
//    (t+2 -> buf0), each issued right after the barrier that retires the
//    last read of the target buffer (write-after-read safe by construction).
//    One vmcnt(0) per 4 phases, 3 phases after issue (loads span 6 barriers).
#define GU_BAR()  do { asm volatile("" ::: "memory"); \
                       __builtin_amdgcn_s_barrier(); \
                       asm volatile("" ::: "memory"); } while (0)
#define GU_LGK0() do { asm volatile("s_waitcnt lgkmcnt(0)" ::: "memory"); \
                       __builtin_amdgcn_sched_barrier(0); } while (0)
#define GU_VMC0() asm volatile("s_waitcnt vmcnt(0)" ::: "memory")

#define GU_STAGE(TILE, BB) do { \
    _Pragma("unroll") \
    for (int j_ = 0; j_ < 8; ++j_) \
      load_lds16(srcp[j_] + (long)(TILE) * 64, smem + (BB) + dstoff[j_]); \
  } while (0)

#define GU_READA(BB, MH) do { \
    const char* ab_ = smem + (BB) + wroff; \
    _Pragma("unroll") \
    for (int mb_ = 0; mb_ < 4; ++mb_) { \
      const int rb_ = ((MH) * 64 + mb_ * 16 + l16) * 128; \
      afr[mb_][0] = *(const bf16x8*)(ab_ + rb_ + koff0); \
      afr[mb_][1] = *(const bf16x8*)(ab_ + rb_ + koff1); \
    } } while (0)

#define GU_READB(BB, NH) do { \
    const char* bb_ = smem + (BB) + 32768 + bhoff; \
    _Pragma("unroll") \
    for (int nb_ = 0; nb_ < 2; ++nb_) { \
      const int rb_ = (brow0 + (NH) * 32 + nb_ * 16) * 128; \
      bfr[NH][nb_][0] = *(const bf16x8*)(bb_ + rb_ + koff0); \
      bfr[NH][nb_][1] = *(const bf16x8*)(bb_ + rb_ + koff1); \
    } } while (0)

#define GU_MFMAQ(MH, NH) do { \
    _Pragma("unroll") \
    for (int mb_ = 0; mb_ < 4; ++mb_) \
      _Pragma("unroll") \
      for (int nb_ = 0; nb_ < 2; ++nb_) { \
        f32x4* a_ = &acc[(MH) * 4 + mb_][(NH) * 2 + nb_]; \
        *a_ = __builtin_amdgcn_mfma_f32_16x16x32_bf16(afr[mb_][0], bfr[NH][nb_][0], *a_, 0, 0, 0); \
        *a_ = __builtin_amdgcn_mfma_f32_16x16x32_bf16(afr[mb_][1], bfr[NH][nb_][1], *a_, 0, 0, 0); \
      } } while (0)

__global__ __launch_bounds__(512, 2) void mlp_gateup256_kernel(
    const bf16* __restrict__ A, const bf16* __restrict__ Bc,
    bf16* __restrict__ out, int M, int Ncat, int K)
{
  (void)M;
  __shared__ __align__(16) char smem[131072];
  const int tid  = threadIdx.x;
  const int wave = tid >> 6, lane = tid & 63;
  const int quad = lane >> 4, l16 = lane & 15;
  const int wr = wave >> 2, wc = wave & 3;       // 2M x 4N wave grid
  const int bm = blockIdx.y << 8, bn = blockIdx.x << 8;
  const int KT = K >> 6;                          // K-tiles of 64

  // swizzled ds_read k-offsets (thread-const): (ks*64+quad*16) ^ ((l16&7)<<4)
  const int koff0 = (quad * 16) ^ ((l16 & 7) << 4);
  const int koff1 = koff0 ^ 64;
  const int wroff = wr * 16384;                   // this wave's A half
  const int bhoff = (wc >> 1) * 16384;            // this wave's B half
  const int brow0 = (wc & 1) * 64 + l16;          // B row base within half

  // Staging: 8 chunks/thread (A/B x half x 2). LDS dest linear
  // (wave-uniform base + lane*16); global source pre-swizzled so that
  // LDS[L] holds the element at logical offset swz(L).
  const int srow = lane >> 3;                     // 0..7
  const int scol = ((lane & 7) ^ srow) << 3;      // swizzled col (elems)
  const bf16* srcp[8]; int dstoff[8];
  #pragma unroll
  for (int op = 0; op < 2; ++op)
    #pragma unroll
    for (int h = 0; h < 2; ++h)
      #pragma unroll
      for (int g = 0; g < 2; ++g) {
        const int j = op * 4 + h * 2 + g;
        const int grow = (op ? bn : bm) + h * 128 + g * 64 + wave * 8 + srow;
        srcp[j] = (op ? Bc : A) + (long)grow * K + scol;
        dstoff[j] = op * 32768 + h * 16384 + g * 8192 + wave * 1024;
      }

  f32x4 acc[8][4] = {};
  bf16x8 afr[4][2];        // current A-half fragments [mb][ks]
  bf16x8 bfr[2][2][2];     // both B halves kept live  [nh][nb][ks]

  // prologue: tile 0 -> buf0 (cold-start drain, once)
  GU_STAGE(0, 0);
  GU_VMC0();
  GU_BAR();

  #pragma unroll 1
  for (int t = 0; t < KT; t += 2) {
    // -- p0: tile t (buf0) Q(0,0); stage t+1 -> buf1 (buf1 retired last iter)
    GU_STAGE(t + 1, 65536);
    GU_READA(0, 0); GU_READB(0, 0);
    GU_BAR(); GU_LGK0();
    __builtin_amdgcn_s_setprio(1); GU_MFMAQ(0, 0); __builtin_amdgcn_s_setprio(0);
    GU_BAR();
    // -- p1: Q(0,1)
    GU_READB(0, 1);
    GU_BAR(); GU_LGK0();
    __builtin_amdgcn_s_setprio(1); GU_MFMAQ(0, 1); __builtin_amdgcn_s_setprio(0);
    GU_BAR();
    // -- p2: Q(1,1)
    GU_READA(0, 1);
    GU_BAR(); GU_LGK0();
    __builtin_amdgcn_s_setprio(1); GU_MFMAQ(1, 1); __builtin_amdgcn_s_setprio(0);
    GU_BAR();
    // -- p3: Q(1,0) (B(0) still in regs); drain t+1 stages before buf1 reads
    __builtin_amdgcn_s_setprio(1); GU_MFMAQ(1, 0); __builtin_amdgcn_s_setprio(0);
    GU_VMC0();
    GU_BAR();
    // -- p4: tile t+1 (buf1) Q(0,0); stage t+2 -> buf0 (buf0 reads retired at p3 bar)
    if (t + 2 < KT) GU_STAGE(t + 2, 0);
    GU_READA(65536, 0); GU_READB(65536, 0);
    GU_BAR(); GU_LGK0();
    __builtin_amdgcn_s_setprio(1); GU_MFMAQ(0, 0); __builtin_amdgcn_s_setprio(0);
    GU_BAR();
    // -- p5: Q(0,1)
    GU_READB(65536, 1);
    GU_BAR(); GU_LGK0();
    __builtin_amdgcn_s_setprio(1); GU_MFMAQ(0, 1); __builtin_amdgcn_s_setprio(0);
    GU_BAR();
    // -- p6: Q(1,1)
    GU_READA(65536, 1);
    GU_BAR(); GU_LGK0();
    __builtin_amdgcn_s_setprio(1); GU_MFMAQ(1, 1); __builtin_amdgcn_s_setprio(0);
    GU_BAR();
    // -- p7: Q(1,0); drain t+2 stages before next-iter buf0 reads
    __builtin_amdgcn_s_setprio(1); GU_MFMAQ(1, 0); __builtin_amdgcn_s_setprio(0);
    GU_VMC0();
    GU_BAR();
  }

  // epilogue: fragment pair (nb even = gate, nb odd = up) -> silu(g)*u
  const long NO = Ncat >> 1;
  const int orow0 = bm + wr * 128 + (quad << 2);
  const int ocol  = (bn >> 1) + wc * 32 + l16;
  #pragma unroll
  for (int ma = 0; ma < 8; ++ma)
    #pragma unroll
    for (int nh = 0; nh < 2; ++nh)
      #pragma unroll
      for (int r = 0; r < 4; ++r) {
        const float g = acc[ma][nh * 2][r];
        const float u = acc[ma][nh * 2 + 1][r];
        out[(long)(orow0 + ma * 16 + r) * NO + ocol + nh * 16] =
            f2b(g / (1.0f + __expf(-g)) * u);
      }
}

// ---------- Down-proj GEMM, shared-B: 512 thr, 256M x 128N tile ----------
// Waves 0-3: rows [bm, bm+128); waves 4-7: rows [bm+128, bm+256). Shared B stage.
// f32 out = acc + res (res may alias out; same-element RMW).
__global__ __launch_bounds__(512) void down_kernel(
    const bf16* __restrict__ A, const bf16* __restrict__ Bt,
    float* __restrict__ out, const float* __restrict__ res,
    int M, int N, int K)
{
  __shared__ __align__(16) char smem[24576];   // A0 8K | A1 8K | B 8K
  const int tid = threadIdx.x;
  const int wave = tid >> 6, lane = tid & 63;
  const int role = wave >> 2, wq = wave & 3;
  const int wm = (wq & 1) << 6, wn = (wq >> 1) << 6;
  const int l16 = lane & 15, quad = lane >> 4;
  const int srow = lane >> 2, scol = (lane & 3) << 3;

  const int bm = blockIdx.y << 8, bn = blockIdx.x << 7;

  // 24 staging chunks of 16 rows x 32 cols: 3 per wave.
  const bf16* sp[3]; char* dp[3];
  #pragma unroll
  for (int j = 0; j < 3; ++j) {
    const int c = 3 * wave + j;
    const int buf = c >> 3, r0 = (c & 7) << 4;
    const bf16* gbase = (buf == 0) ? A + (long)bm * K
                      : (buf == 1) ? A + (long)(bm + 128) * K
                                   : Bt + (long)bn * K;
    sp[j] = gbase + (long)(r0 + srow) * K + scol;
    dp[j] = smem + buf * 8192 + (c & 7) * 1024;
  }
  const bf16* Asb = (const bf16*)(smem + role * 8192);
  const bf16* Bsb = (const bf16*)(smem + 16384);

  f32x4 acc[4][4] = {};

  for (int k0 = 0; k0 < K; k0 += 32) {
    __syncthreads();
    #pragma unroll
    for (int j = 0; j < 3; ++j) load_lds16(sp[j] + k0, dp[j]);
    __syncthreads();
    bf16x8 af[4], bfr[4];
    #pragma unroll
    for (int i = 0; i < 4; ++i) {
      af[i]  = *(const bf16x8*)&Asb[(wm + i * 16 + l16) * 32 + quad * 8];
      bfr[i] = *(const bf16x8*)&Bsb[(wn + i * 16 + l16) * 32 + quad * 8];
    }
    #pragma unroll
    for (int mb = 0; mb < 4; ++mb)
      #pragma unroll
      for (int nb = 0; nb < 4; ++nb)
        acc[mb][nb] = __builtin_amdgcn_mfma_f32_16x16x32_bf16(af[mb], bfr[nb], acc[mb][nb], 0, 0, 0);
  }

  const int crow = bm + role * 128 + wm + (quad << 2);
  const int ccol = bn + wn + l16;
  #pragma unroll
  for (int mb = 0; mb < 4; ++mb)
    #pragma unroll
    for (int nb = 0; nb < 4; ++nb)
      #pragma unroll
      for (int r = 0; r < 4; ++r) {
        const long idx = (long)(crow + mb * 16 + r) * N + (ccol + nb * 16);
        out[idx] = acc[mb][nb][r] + res[idx];
      }
}

// ---------- RoPE + layout: qkv bf16 [BT][3072] -> Q [B][NH][T][HD],
//            K [B][NKV][T][HD], V^T [B][NKV][HD][T] ----------
__global__ __launch_bounds__(256) void rope_kernel(
    const bf16* __restrict__ qkv, bf16* __restrict__ Q,
    bf16* __restrict__ K, bf16* __restrict__ VT)
{
  const int t = blockIdx.x, b = blockIdx.y;
  const bf16* row = qkv + (long)(b * T_ + t) * QKVN_;
  const float tf = (float)t;  // positions = t (segment_ids all-ones, cur_ind=0)
  for (int idx = threadIdx.x; idx < NH_ * HD_; idx += 256) {
    const int head = idx >> 7, hd = idx & 127;
    const float v = b2f(row[idx]);
    float o;
    if (hd < 64) {
      const int j = hd & 31;
      const float ang = tf * expf(-(float)j * 0.28782313662425574f); // ln(1e4)/32
      const float sn = sinf(ang), cs = cosf(ang);
      o = (hd < 32) ? (v * cs - b2f(row[idx + 32]) * sn)
                    : (v * cs + b2f(row[idx - 32]) * sn);
    } else o = v;
    Q[((long)(b * NH_ + head) * T_ + t) * HD_ + hd] = f2b(o);
  }
  for (int idx = threadIdx.x; idx < NKV_ * HD_; idx += 256) {
    const int kv = idx >> 7, hd = idx & 127;
    const float v = b2f(row[NH_ * HD_ + idx]);
    float o;
    if (hd < 64) {
      const int j = hd & 31;
      const float ang = tf * expf(-(float)j * 0.28782313662425574f);
      const float sn = sinf(ang), cs = cosf(ang);
      o = (hd < 32) ? (v * cs - b2f(row[NH_ * HD_ + idx + 32]) * sn)
                    : (v * cs + b2f(row[NH_ * HD_ + idx - 32]) * sn);
    } else o = v;
    K[((long)(b * NKV_ + kv) * T_ + t) * HD_ + hd] = f2b(o);
  }
  for (int idx = threadIdx.x; idx < NKV_ * HD_; idx += 256) {
    const int kv = idx >> 7, vd = idx & 127;
    VT[((long)(b * NKV_ + kv) * HD_ + vd) * T_ + t] = row[(NH_ + NKV_) * HD_ + idx];
  }
}

// ---------- Flash attention: 64-row Q tile per block, window 1024, sink ----------
__global__ __launch_bounds__(256) void attn_kernel(
    const bf16* __restrict__ Q, const bf16* __restrict__ Kg,
    const bf16* __restrict__ VTg, const float* __restrict__ sink,
    bf16* __restrict__ attnb)
{
  __shared__ __align__(16) bf16 Qs[64 * 136];   // padded: stride 136 elems (272B)
  __shared__ __align__(16) bf16 Ks[64 * 136];
  __shared__ __align__(16) bf16 Vs[128 * 72];   // V^T tile, stride 72 (144B)
  __shared__ __align__(16) bf16 Ps[64 * 72];    // P round-trip C-layout -> A-layout

  const int qt = blockIdx.x;
  const int bh = blockIdx.y;
  const int b = bh >> 4, h = bh & 15;
  const int kvh = h >> 2;            // GQA: 4 q-heads per kv-head
  const int t0 = qt * 64;
  const int tid = threadIdx.x;
  const int wave = tid >> 6, lane = tid & 63;
  const int quad = lane >> 4, l16 = lane & 15;

  const bf16* Qp = Q + ((long)(b * NH_ + h) * T_ + t0) * HD_;
  #pragma unroll
  for (int c = tid; c < 1024; c += 256) {
    const int r = c >> 4, cc = (c & 15) << 3;
    *(uint4*)&Qs[r * 136 + cc] = *(const uint4*)&Qp[r * HD_ + cc];
  }

  float m_i[4], l_i[4];
  const float sb = sink[h];
  #pragma unroll
  for (int r = 0; r < 4; ++r) { m_i[r] = sb; l_i[r] = 1.0f; }  // sink column
  f32x4 Oacc[8] = {};

  const int st_lo = (qt > 16) ? (qt - 16) : 0;
  for (int st = st_lo; st <= qt; ++st) {
    const int s0 = st * 64;
    __syncthreads();
    const bf16* Kp = Kg + ((long)(b * NKV_ + kvh) * T_ + s0) * HD_;
    #pragma unroll
    for (int c = tid; c < 1024; c += 256) {
      const int r = c >> 4, cc = (c & 15) << 3;
      *(uint4*)&Ks[r * 136 + cc] = *(const uint4*)&Kp[r * HD_ + cc];
    }
    const bf16* Vp = VTg + (long)(b * NKV_ + kvh) * HD_ * T_ + s0;
    #pragma unroll
    for (int c = tid; c < 1024; c += 256) {
      const int r = c >> 3, cc = (c & 7) << 3;
      *(uint4*)&Vs[r * 72 + cc] = *(const uint4*)&Vp[(long)r * T_ + cc];
    }
    __syncthreads();

    // S = Q K^T (each wave: its 16 Q rows x 64 s cols)
    f32x4 sacc[4] = {};
    #pragma unroll
    for (int kb = 0; kb < 4; ++kb) {
      const bf16x8 aq = *(const bf16x8*)&Qs[(wave * 16 + l16) * 136 + kb * 32 + quad * 8];
      #pragma unroll
      for (int nb = 0; nb < 4; ++nb) {
        const bf16x8 bk = *(const bf16x8*)&Ks[(nb * 16 + l16) * 136 + kb * 32 + quad * 8];
        sacc[nb] = __builtin_amdgcn_mfma_f32_16x16x32_bf16(aq, bk, sacc[nb], 0, 0, 0);
      }
    }

    // mask + online softmax (rows live at quad*4+r, cols at l16)
    float sv[4][4];
    float rmax[4] = {-INFINITY, -INFINITY, -INFINITY, -INFINITY};
    const int colb = s0 + l16;
    const int rowb = t0 + wave * 16 + quad * 4;
    #pragma unroll
    for (int nb = 0; nb < 4; ++nb)
      #pragma unroll
      for (int r = 0; r < 4; ++r) {
        float v = sacc[nb][r] * 0.08838834764831845f;  // HD^-0.5
        const int s = colb + nb * 16, tq = rowb + r;
        if (s > tq || s < tq - (WIN_ - 1)) v = -INFINITY;
        sv[nb][r] = v;
        rmax[r] = fmaxf(rmax[r], v);
      }
    #pragma unroll
    for (int r = 0; r < 4; ++r)
      #pragma unroll
      for (int off = 1; off < 16; off <<= 1)
        rmax[r] = fmaxf(rmax[r], __shfl_xor(rmax[r], off, 64));
    float alpha[4], rsum[4];
    #pragma unroll
    for (int r = 0; r < 4; ++r) {
      const float mn = fmaxf(m_i[r], rmax[r]);
      alpha[r] = __expf(m_i[r] - mn);
      m_i[r] = mn;
      rsum[r] = 0.0f;
    }
    #pragma unroll
    for (int nb = 0; nb < 4; ++nb)
      #pragma unroll
      for (int r = 0; r < 4; ++r) {
        const float p = __expf(sv[nb][r] - m_i[r]);   // masked -> exp(-inf)=0
        rsum[r] += p;
        Ps[(wave * 16 + quad * 4 + r) * 72 + nb * 16 + l16] = f2b(p);
      }
    #pragma unroll
    for (int r = 0; r < 4; ++r) {
      #pragma unroll
      for (int off = 1; off < 16; off <<= 1)
        rsum[r] += __shfl_xor(rsum[r], off, 64);
      l_i[r] = l_i[r] * alpha[r] + rsum[r];
    }
    #pragma unroll
    for (int nb = 0; nb < 8; ++nb)
      #pragma unroll
      for (int r = 0; r < 4; ++r)
        Oacc[nb][r] *= alpha[r];
    __syncthreads();  // P visible before A-layout re-read

    // O += P V  (A = P rows of this wave, B = V^T tile)
    #pragma unroll
    for (int ks = 0; ks < 2; ++ks) {
      const bf16x8 ap = *(const bf16x8*)&Ps[(wave * 16 + l16) * 72 + ks * 32 + quad * 8];
      #pragma unroll
      for (int nb = 0; nb < 8; ++nb) {
        const bf16x8 bv = *(const bf16x8*)&Vs[(nb * 16 + l16) * 72 + ks * 32 + quad * 8];
        Oacc[nb] = __builtin_amdgcn_mfma_f32_16x16x32_bf16(ap, bv, Oacc[nb], 0, 0, 0);
      }
    }
  }

  float rcp[4];
  #pragma unroll
  for (int r = 0; r < 4; ++r) rcp[r] = 1.0f / l_i[r];
  bf16* outp = attnb + ((long)(b * T_ + t0 + wave * 16 + quad * 4)) * EMB_ + h * HD_ + l16;
  #pragma unroll
  for (int nb = 0; nb < 8; ++nb)
    #pragma unroll
    for (int r = 0; r < 4; ++r)
      outp[(long)r * EMB_ + nb * 16] = f2b(Oacc[nb][r] * rcp[r]);
}

extern "C" void kernel_launch(void* const* d_in, const int* in_sizes, int n_in,
                              void* d_out, int out_size, void* d_ws, size_t ws_size,
                              hipStream_t stream)
{
  (void)in_sizes; (void)n_in; (void)out_size; (void)ws_size;
  const float* x    = (const float*)d_in[0];
  const float* wq   = (const float*)d_in[2];
  const float* wk   = (const float*)d_in[3];
  const float* wv   = (const float*)d_in[4];
  const float* wo   = (const float*)d_in[5];
  const float* sink = (const float*)d_in[6];
  const float* gw   = (const float*)d_in[7];
  const float* uw   = (const float*)d_in[8];
  const float* dw   = (const float*)d_in[9];
  const float* n1   = (const float*)d_in[10];
  const float* n2   = (const float*)d_in[11];

  // ---- workspace: 184.5 MB via phase aliasing ----
  char* base = (char*)d_ws;
  bf16*  hbuf  = (bf16*)base;                                   // 16,777,216
  char*  R1    = base + (size_t)16777216;                       // 67,108,864
  char*  R2    = R1   + (size_t)67108864;                       // 33,554,432
  bf16*  mact  = (bf16*)(R2 + (size_t)33554432);                // 67,108,864

  // phase A views
  bf16* qkv   = (bf16*)R1;                                      // 25,165,824
  bf16* Qb    = (bf16*)(R1 + 25165824);                         // 16,777,216
  bf16* Kb    = (bf16*)(R1 + 41943040);                         //  4,194,304
  bf16* VTb   = (bf16*)(R1 + 46137344);                         //  4,194,304
  bf16* attnb = (bf16*)R1;            // aliases qkv (dead after rope)
  bf16* wqkvT = (bf16*)R2;                                      // 12,582,912
  bf16* woT   = (bf16*)(R2 + 12582912);                         //  8,388,608
  // phase B views
  bf16* Bcat  = (bf16*)R1;            // 16384 x 2048 bf16 = 67,108,864 (gate/up interleaved)
  bf16* downT = (bf16*)R2;                                      // 33,554,432
  float* x1   = (float*)d_out;        // residual after attention

  const dim3 tb(32, 8);
  // ---- phase A: attention ----
  transpose_kernel<<<dim3( 64,  64), tb, 0, stream>>>(wq, wqkvT,                      EMB_, EMB_, 1, 0);
  transpose_kernel<<<dim3( 16,  64), tb, 0, stream>>>(wk, wqkvT + (size_t)2048*EMB_,  EMB_, 512, 1, 0);
  transpose_kernel<<<dim3( 16,  64), tb, 0, stream>>>(wv, wqkvT + (size_t)2560*EMB_,  EMB_, 512, 1, 0);
  transpose_kernel<<<dim3( 64,  64), tb, 0, stream>>>(wo, woT,                        EMB_, EMB_, 1, 0);

  rmsnorm_kernel<<<BT_, 256, 0, stream>>>(x, n1, hbuf);
  gemm_kernel<0><<<dim3(QKVN_/128, BT_/128), 256, 0, stream>>>(hbuf, wqkvT, qkv, nullptr, BT_, QKVN_, EMB_);
  rope_kernel<<<dim3(T_, B_), 256, 0, stream>>>(qkv, Qb, Kb, VTb);
  attn_kernel<<<dim3(T_/64, B_*NH_), 256, 0, stream>>>(Qb, Kb, VTb, sink, attnb);
  gemm_kernel<1><<<dim3(EMB_/128, BT_/128), 256, 0, stream>>>(attnb, woT, x1, x, BT_, EMB_, EMB_);

  // ---- phase B: MLP ----
  rmsnorm_kernel<<<BT_, 256, 0, stream>>>(x1, n2, hbuf);
  transpose_kernel<<<dim3(256,  64), tb, 0, stream>>>(gw, Bcat, EMB_, MLPD_, 2, 0);
  transpose_kernel<<<dim3(256,  64), tb, 0, stream>>>(uw, Bcat, EMB_, MLPD_, 2, 1);
  mlp_gateup256_kernel<<<dim3((2*MLPD_)/256, BT_/256), 512, 0, stream>>>(hbuf, Bcat, mact, BT_, 2*MLPD_, EMB_);
  transpose_kernel<<<dim3( 64, 256), tb, 0, stream>>>(dw, downT, MLPD_, EMB_, 1, 0);
  down_kernel<<<dim3(EMB_/128, BT_/256), 512, 0, stream>>>(mact, downT, (float*)d_out, x1, BT_, EMB_, MLPD_);
}

// Round 3
// 962.321 us; speedup vs baseline: 1.1659x; 1.1397x over previous
//
#include <hip/hip_runtime.h>
#include <hip/hip_bf16.h>
#include <stdint.h>

#define B_    2
#define T_    2048
#define EMB_  2048
#define NH_   16
#define NKV_  4
#define HD_   128
#define MLPD_ 8192
#define WIN_  1024
#define BT_   (B_ * T_)     // 4096 rows
#define QKVN_ 3072          // NH*HD + NKV*HD + NKV*HD

typedef __bf16 bf16;
typedef __bf16 bf16x8 __attribute__((ext_vector_type(8)));
typedef float  f32x4  __attribute__((ext_vector_type(4)));

__device__ __forceinline__ bf16 f2b(float f) {
  __hip_bfloat16 h = __float2bfloat16(f);
  return *reinterpret_cast<bf16*>(&h);
}
__device__ __forceinline__ float b2f(bf16 b) {
  __hip_bfloat16 h = *reinterpret_cast<__hip_bfloat16*>(&b);
  return __bfloat162float(h);
}

__device__ __forceinline__ void load_lds16(const void* g, void* l) {
  __builtin_amdgcn_global_load_lds(
      (const __attribute__((address_space(1))) void*)g,
      (__attribute__((address_space(3))) void*)l, 16, 0, 0);
}

// ---------- transpose f32 [R][C] -> bf16 [remap(C)][R] ----------
__global__ __launch_bounds__(256) void transpose_kernel(
    const float* __restrict__ in, bf16* __restrict__ out, int R, int C,
    int rmul, int radd)
{
  __shared__ float tile[32][33];
  const int tx = threadIdx.x, ty = threadIdx.y;  // blockDim (32,8)
  const int c0 = blockIdx.x * 32, r0 = blockIdx.y * 32;
  #pragma unroll
  for (int i = 0; i < 32; i += 8)
    tile[ty + i][tx] = in[(long)(r0 + ty + i) * C + c0 + tx];
  __syncthreads();
  #pragma unroll
  for (int i = 0; i < 32; i += 8) {
    const int oc = c0 + ty + i;
    const int orow = (oc & 15) + (((oc >> 4) * rmul + radd) << 4);
    out[(long)orow * R + r0 + tx] = f2b(tile[tx][ty + i]);
  }
}

// ---------- RMSNorm: f32 row -> bf16 row ----------
__global__ __launch_bounds__(256) void rmsnorm_kernel(
    const float* __restrict__ x, const float* __restrict__ scale,
    bf16* __restrict__ out)
{
  const long row = blockIdx.x;
  const float* xr = x + row * EMB_;
  bf16* orow = out + row * EMB_;
  const float4 v0 = ((const float4*)xr)[threadIdx.x];
  const float4 v1 = ((const float4*)xr)[threadIdx.x + 256];
  float ss = v0.x*v0.x + v0.y*v0.y + v0.z*v0.z + v0.w*v0.w
           + v1.x*v1.x + v1.y*v1.y + v1.z*v1.z + v1.w*v1.w;
  #pragma unroll
  for (int off = 32; off >= 1; off >>= 1) ss += __shfl_xor(ss, off, 64);
  __shared__ float red[4];
  if ((threadIdx.x & 63) == 0) red[threadIdx.x >> 6] = ss;
  __syncthreads();
  const float tot = red[0] + red[1] + red[2] + red[3];
  const float rs = rsqrtf(tot * (1.0f / EMB_) + 1e-6f);
  const float4 s0 = ((const float4*)scale)[threadIdx.x];
  const float4 s1 = ((const float4*)scale)[threadIdx.x + 256];
  const int c0 = threadIdx.x * 4;
  orow[c0 + 0]    = f2b(v0.x * rs * (1.0f + s0.x));
  orow[c0 + 1]    = f2b(v0.y * rs * (1.0f + s0.y));
  orow[c0 + 2]    = f2b(v0.z * rs * (1.0f + s0.z));
  orow[c0 + 3]    = f2b(v0.w * rs * (1.0f + s0.w));
  orow[c0 + 1024] = f2b(v1.x * rs * (1.0f + s1.x));
  orow[c0 + 1025] = f2b(v1.y * rs * (1.0f + s1.y));
  orow[c0 + 1026] = f2b(v1.z * rs * (1.0f + s1.z));
  orow[c0 + 1027] = f2b(v1.w * rs * (1.0f + s1.w));
}

// ============ deep-pipelined 128M x 256N GEMM (3-buf, counted vmcnt) ============
#define DG_BAR()  do { asm volatile("" ::: "memory"); \
                       __builtin_amdgcn_s_barrier(); \
                       asm volatile("" ::: "memory"); } while (0)
#define DG_LGK0() do { asm volatile("s_waitcnt lgkmcnt(0)" ::: "memory"); \
                       __builtin_amdgcn_sched_barrier(0); } while (0)

#define DG_STAGE(TILE, BB) do { \
    _Pragma("unroll") \
    for (int j_ = 0; j_ < 6; ++j_) \
      load_lds16(srcp[j_] + (long)(TILE) * 64, smem + (BB) + dstoff[j_]); \
  } while (0)

#define DG_READA(BB) do { \
    _Pragma("unroll") \
    for (int mb_ = 0; mb_ < 4; ++mb_) { \
      const int rb_ = (wr * 64 + mb_ * 16 + l16) * 128; \
      afr[mb_][0] = *(const bf16x8*)(smem + (BB) + rb_ + koff0); \
      afr[mb_][1] = *(const bf16x8*)(smem + (BB) + rb_ + koff1); \
    } } while (0)

#define DG_READB(BB, NH) do { \
    _Pragma("unroll") \
    for (int nb_ = 0; nb_ < 2; ++nb_) { \
      const int rb_ = 16384 + (wc * 64 + (NH) * 32 + nb_ * 16 + l16) * 128; \
      bfr[nb_][0] = *(const bf16x8*)(smem + (BB) + rb_ + koff0); \
      bfr[nb_][1] = *(const bf16x8*)(smem + (BB) + rb_ + koff1); \
    } } while (0)

#define DG_MFMA(NH) do { \
    _Pragma("unroll") \
    for (int mb_ = 0; mb_ < 4; ++mb_) \
      _Pragma("unroll") \
      for (int nb_ = 0; nb_ < 2; ++nb_) { \
        f32x4* a_ = &acc[mb_][(NH) * 2 + nb_]; \
        *a_ = __builtin_amdgcn_mfma_f32_16x16x32_bf16(afr[mb_][0], bfr[nb_][0], *a_, 0, 0, 0); \
        *a_ = __builtin_amdgcn_mfma_f32_16x16x32_bf16(afr[mb_][1], bfr[nb_][1], *a_, 0, 0, 0); \
      } } while (0)

template <int EPI>
__global__ __launch_bounds__(512, 2) void gemm256_kernel(
    const bf16* __restrict__ A, const bf16* __restrict__ Bt,
    void* __restrict__ out, const float* __restrict__ res,
    int M, int N, int K)
{
  (void)M;
  __shared__ __align__(16) char smem[147456];   // 3 x 48 KiB rotating buffers
  const int tid  = threadIdx.x;
  const int wave = tid >> 6, lane = tid & 63;
  const int quad = lane >> 4, l16 = lane & 15;
  const int wr = wave >> 2, wc = wave & 3;        // 2M x 4N wave grid
  const int bm = blockIdx.y << 7, bn = blockIdx.x << 8;
  const int KT = K >> 6;

  const int koff0 = (quad * 16) ^ ((l16 & 7) << 4);
  const int koff1 = koff0 ^ 64;

  // staging: 48 chunks of 8 rows x 64 cols (1 KB); 6 per wave.
  // LDS dest linear; global col pre-swizzled (involution matches read XOR).
  const int srow = lane >> 3;
  const int scol = ((lane & 7) ^ srow) << 3;
  const bf16* srcp[6]; int dstoff[6];
  #pragma unroll
  for (int j = 0; j < 6; ++j) {
    const int c = 6 * wave + j;
    const int grow = (c < 16) ? (bm + c * 8 + srow) : (bn + (c - 16) * 8 + srow);
    const bf16* gbase = (c < 16) ? A : Bt;
    srcp[j] = gbase + (long)grow * K + scol;
    dstoff[j] = c * 1024;
  }

  f32x4 acc[4][4] = {};
  bf16x8 afr[4][2];
  bf16x8 bfr[2][2];

  int base0 = 0, base1 = 49152, base2 = 98304;

  // prologue: tiles 0,1 in flight; hard drain once (cold-start safety)
  DG_STAGE(0, base0);
  DG_STAGE(1, base1);
  asm volatile("s_waitcnt vmcnt(0)" ::: "memory");
  DG_BAR();

  #pragma unroll 1
  for (int t = 0; t < KT; ++t) {
    // p0: issue batch t+2 -> base2; compute NH0 of tile t (base0 ready)
    if (t + 2 < KT) DG_STAGE(t + 2, base2);
    DG_READA(base0); DG_READB(base0, 0);
    DG_BAR(); DG_LGK0();
    __builtin_amdgcn_s_setprio(1); DG_MFMA(0); __builtin_amdgcn_s_setprio(0);
    DG_BAR();
    // p1: compute NH1; retire batch t+1 (t+2's 6 loads stay in flight)
    DG_READB(base0, 1);
    DG_BAR(); DG_LGK0();
    __builtin_amdgcn_s_setprio(1); DG_MFMA(1); __builtin_amdgcn_s_setprio(0);
    if (t + 2 < KT) { asm volatile("s_waitcnt vmcnt(6)" ::: "memory"); }
    else            { asm volatile("s_waitcnt vmcnt(0)" ::: "memory"); }
    DG_BAR();
    const int r_ = base0; base0 = base1; base1 = base2; base2 = r_;
  }

  const int crow = bm + wr * 64 + (quad << 2);
  const int ccol = bn + wc * 64 + l16;
  #pragma unroll
  for (int mb = 0; mb < 4; ++mb)
    #pragma unroll
    for (int nb = 0; nb < 4; ++nb)
      #pragma unroll
      for (int r = 0; r < 4; ++r) {
        const long idx = (long)(crow + mb * 16 + r) * N + (ccol + nb * 16);
        const float v = acc[mb][nb][r];
        if (EPI == 0) {
          ((bf16*)out)[idx] = f2b(v);
        } else {
          ((float*)out)[idx] = v + res[idx];
        }
      }
}

// ================== Fused gate+up 256x256 8-phase GEMM ==================
#define GU_BAR()  do { asm volatile("" ::: "memory"); \
                       __builtin_amdgcn_s_barrier(); \
                       asm volatile("" ::: "memory"); } while (0)
#define GU_LGK0() do { asm volatile("s_waitcnt lgkmcnt(0)" ::: "memory"); \
                       __builtin_amdgcn_sched_barrier(0); } while (0)
#define GU_VMC0() asm volatile("s_waitcnt vmcnt(0)" ::: "memory")

#define GU_STAGE(TILE, BB) do { \
    _Pragma("unroll") \
    for (int j_ = 0; j_ < 8; ++j_) \
      load_lds16(srcp[j_] + (long)(TILE) * 64, smem + (BB) + dstoff[j_]); \
  } while (0)

#define GU_READA(BB, MH) do { \
    const char* ab_ = smem + (BB) + wroff; \
    _Pragma("unroll") \
    for (int mb_ = 0; mb_ < 4; ++mb_) { \
      const int rb_ = ((MH) * 64 + mb_ * 16 + l16) * 128; \
      afr[mb_][0] = *(const bf16x8*)(ab_ + rb_ + koff0); \
      afr[mb_][1] = *(const bf16x8*)(ab_ + rb_ + koff1); \
    } } while (0)

#define GU_READB(BB, NH) do { \
    const char* bb_ = smem + (BB) + 32768 + bhoff; \
    _Pragma("unroll") \
    for (int nb_ = 0; nb_ < 2; ++nb_) { \
      const int rb_ = (brow0 + (NH) * 32 + nb_ * 16) * 128; \
      bfr[NH][nb_][0] = *(const bf16x8*)(bb_ + rb_ + koff0); \
      bfr[NH][nb_][1] = *(const bf16x8*)(bb_ + rb_ + koff1); \
    } } while (0)

#define GU_MFMAQ(MH, NH) do { \
    _Pragma("unroll") \
    for (int mb_ = 0; mb_ < 4; ++mb_) \
      _Pragma("unroll") \
      for (int nb_ = 0; nb_ < 2; ++nb_) { \
        f32x4* a_ = &acc[(MH) * 4 + mb_][(NH) * 2 + nb_]; \
        *a_ = __builtin_amdgcn_mfma_f32_16x16x32_bf16(afr[mb_][0], bfr[NH][nb_][0], *a_, 0, 0, 0); \
        *a_ = __builtin_amdgcn_mfma_f32_16x16x32_bf16(afr[mb_][1], bfr[NH][nb_][1], *a_, 0, 0, 0); \
      } } while (0)

__global__ __launch_bounds__(512, 2) void mlp_gateup256_kernel(
    const bf16* __restrict__ A, const bf16* __restrict__ Bc,
    bf16* __restrict__ out, int M, int Ncat, int K)
{
  (void)M;
  __shared__ __align__(16) char smem[131072];
  const int tid  = threadIdx.x;
  const int wave = tid >> 6, lane = tid & 63;
  const int quad = lane >> 4, l16 = lane & 15;
  const int wr = wave >> 2, wc = wave & 3;
  const int bm = blockIdx.y << 8, bn = blockIdx.x << 8;
  const int KT = K >> 6;

  const int koff0 = (quad * 16) ^ ((l16 & 7) << 4);
  const int koff1 = koff0 ^ 64;
  const int wroff = wr * 16384;
  const int bhoff = (wc >> 1) * 16384;
  const int brow0 = (wc & 1) * 64 + l16;

  const int srow = lane >> 3;
  const int scol = ((lane & 7) ^ srow) << 3;
  const bf16* srcp[8]; int dstoff[8];
  #pragma unroll
  for (int op = 0; op < 2; ++op)
    #pragma unroll
    for (int h = 0; h < 2; ++h)
      #pragma unroll
      for (int g = 0; g < 2; ++g) {
        const int j = op * 4 + h * 2 + g;
        const int grow = (op ? bn : bm) + h * 128 + g * 64 + wave * 8 + srow;
        srcp[j] = (op ? Bc : A) + (long)grow * K + scol;
        dstoff[j] = op * 32768 + h * 16384 + g * 8192 + wave * 1024;
      }

  f32x4 acc[8][4] = {};
  bf16x8 afr[4][2];
  bf16x8 bfr[2][2][2];

  GU_STAGE(0, 0);
  GU_VMC0();
  GU_BAR();

  #pragma unroll 1
  for (int t = 0; t < KT; t += 2) {
    GU_STAGE(t + 1, 65536);
    GU_READA(0, 0); GU_READB(0, 0);
    GU_BAR(); GU_LGK0();
    __builtin_amdgcn_s_setprio(1); GU_MFMAQ(0, 0); __builtin_amdgcn_s_setprio(0);
    GU_BAR();
    GU_READB(0, 1);
    GU_BAR(); GU_LGK0();
    __builtin_amdgcn_s_setprio(1); GU_MFMAQ(0, 1); __builtin_amdgcn_s_setprio(0);
    GU_BAR();
    GU_READA(0, 1);
    GU_BAR(); GU_LGK0();
    __builtin_amdgcn_s_setprio(1); GU_MFMAQ(1, 1); __builtin_amdgcn_s_setprio(0);
    GU_BAR();
    __builtin_amdgcn_s_setprio(1); GU_MFMAQ(1, 0); __builtin_amdgcn_s_setprio(0);
    GU_VMC0();
    GU_BAR();
    if (t + 2 < KT) GU_STAGE(t + 2, 0);
    GU_READA(65536, 0); GU_READB(65536, 0);
    GU_BAR(); GU_LGK0();
    __builtin_amdgcn_s_setprio(1); GU_MFMAQ(0, 0); __builtin_amdgcn_s_setprio(0);
    GU_BAR();
    GU_READB(65536, 1);
    GU_BAR(); GU_LGK0();
    __builtin_amdgcn_s_setprio(1); GU_MFMAQ(0, 1); __builtin_amdgcn_s_setprio(0);
    GU_BAR();
    GU_READA(65536, 1);
    GU_BAR(); GU_LGK0();
    __builtin_amdgcn_s_setprio(1); GU_MFMAQ(1, 1); __builtin_amdgcn_s_setprio(0);
    GU_BAR();
    __builtin_amdgcn_s_setprio(1); GU_MFMAQ(1, 0); __builtin_amdgcn_s_setprio(0);
    GU_VMC0();
    GU_BAR();
  }

  const long NO = Ncat >> 1;
  const int orow0 = bm + wr * 128 + (quad << 2);
  const int ocol  = (bn >> 1) + wc * 32 + l16;
  #pragma unroll
  for (int ma = 0; ma < 8; ++ma)
    #pragma unroll
    for (int nh = 0; nh < 2; ++nh)
      #pragma unroll
      for (int r = 0; r < 4; ++r) {
        const float g = acc[ma][nh * 2][r];
        const float u = acc[ma][nh * 2 + 1][r];
        out[(long)(orow0 + ma * 16 + r) * NO + ocol + nh * 16] =
            f2b(g / (1.0f + __expf(-g)) * u);
      }
}

// ---------- RoPE + layout ----------
__global__ __launch_bounds__(256) void rope_kernel(
    const bf16* __restrict__ qkv, bf16* __restrict__ Q,
    bf16* __restrict__ K, bf16* __restrict__ VT)
{
  const int t = blockIdx.x, b = blockIdx.y;
  const bf16* row = qkv + (long)(b * T_ + t) * QKVN_;
  const float tf = (float)t;
  for (int idx = threadIdx.x; idx < NH_ * HD_; idx += 256) {
    const int head = idx >> 7, hd = idx & 127;
    const float v = b2f(row[idx]);
    float o;
    if (hd < 64) {
      const int j = hd & 31;
      const float ang = tf * expf(-(float)j * 0.28782313662425574f);
      const float sn = sinf(ang), cs = cosf(ang);
      o = (hd < 32) ? (v * cs - b2f(row[idx + 32]) * sn)
                    : (v * cs + b2f(row[idx - 32]) * sn);
    } else o = v;
    Q[((long)(b * NH_ + head) * T_ + t) * HD_ + hd] = f2b(o);
  }
  for (int idx = threadIdx.x; idx < NKV_ * HD_; idx += 256) {
    const int kv = idx >> 7, hd = idx & 127;
    const float v = b2f(row[NH_ * HD_ + idx]);
    float o;
    if (hd < 64) {
      const int j = hd & 31;
      const float ang = tf * expf(-(float)j * 0.28782313662425574f);
      const float sn = sinf(ang), cs = cosf(ang);
      o = (hd < 32) ? (v * cs - b2f(row[NH_ * HD_ + idx + 32]) * sn)
                    : (v * cs + b2f(row[NH_ * HD_ + idx - 32]) * sn);
    } else o = v;
    K[((long)(b * NKV_ + kv) * T_ + t) * HD_ + hd] = f2b(o);
  }
  for (int idx = threadIdx.x; idx < NKV_ * HD_; idx += 256) {
    const int kv = idx >> 7, vd = idx & 127;
    VT[((long)(b * NKV_ + kv) * HD_ + vd) * T_ + t] = row[(NH_ + NKV_) * HD_ + idx];
  }
}

// ---------- Flash attention ----------
__global__ __launch_bounds__(256) void attn_kernel(
    const bf16* __restrict__ Q, const bf16* __restrict__ Kg,
    const bf16* __restrict__ VTg, const float* __restrict__ sink,
    bf16* __restrict__ attnb)
{
  __shared__ __align__(16) bf16 Qs[64 * 136];
  __shared__ __align__(16) bf16 Ks[64 * 136];
  __shared__ __align__(16) bf16 Vs[128 * 72];
  __shared__ __align__(16) bf16 Ps[64 * 72];

  const int qt = blockIdx.x;
  const int bh = blockIdx.y;
  const int b = bh >> 4, h = bh & 15;
  const int kvh = h >> 2;
  const int t0 = qt * 64;
  const int tid = threadIdx.x;
  const int wave = tid >> 6, lane = tid & 63;
  const int quad = lane >> 4, l16 = lane & 15;

  const bf16* Qp = Q + ((long)(b * NH_ + h) * T_ + t0) * HD_;
  #pragma unroll
  for (int c = tid; c < 1024; c += 256) {
    const int r = c >> 4, cc = (c & 15) << 3;
    *(uint4*)&Qs[r * 136 + cc] = *(const uint4*)&Qp[r * HD_ + cc];
  }

  float m_i[4], l_i[4];
  const float sb = sink[h];
  #pragma unroll
  for (int r = 0; r < 4; ++r) { m_i[r] = sb; l_i[r] = 1.0f; }
  f32x4 Oacc[8] = {};

  const int st_lo = (qt > 16) ? (qt - 16) : 0;
  for (int st = st_lo; st <= qt; ++st) {
    const int s0 = st * 64;
    __syncthreads();
    const bf16* Kp = Kg + ((long)(b * NKV_ + kvh) * T_ + s0) * HD_;
    #pragma unroll
    for (int c = tid; c < 1024; c += 256) {
      const int r = c >> 4, cc = (c & 15) << 3;
      *(uint4*)&Ks[r * 136 + cc] = *(const uint4*)&Kp[r * HD_ + cc];
    }
    const bf16* Vp = VTg + (long)(b * NKV_ + kvh) * HD_ * T_ + s0;
    #pragma unroll
    for (int c = tid; c < 1024; c += 256) {
      const int r = c >> 3, cc = (c & 7) << 3;
      *(uint4*)&Vs[r * 72 + cc] = *(const uint4*)&Vp[(long)r * T_ + cc];
    }
    __syncthreads();

    f32x4 sacc[4] = {};
    #pragma unroll
    for (int kb = 0; kb < 4; ++kb) {
      const bf16x8 aq = *(const bf16x8*)&Qs[(wave * 16 + l16) * 136 + kb * 32 + quad * 8];
      #pragma unroll
      for (int nb = 0; nb < 4; ++nb) {
        const bf16x8 bk = *(const bf16x8*)&Ks[(nb * 16 + l16) * 136 + kb * 32 + quad * 8];
        sacc[nb] = __builtin_amdgcn_mfma_f32_16x16x32_bf16(aq, bk, sacc[nb], 0, 0, 0);
      }
    }

    float sv[4][4];
    float rmax[4] = {-INFINITY, -INFINITY, -INFINITY, -INFINITY};
    const int colb = s0 + l16;
    const int rowb = t0 + wave * 16 + quad * 4;
    #pragma unroll
    for (int nb = 0; nb < 4; ++nb)
      #pragma unroll
      for (int r = 0; r < 4; ++r) {
        float v = sacc[nb][r] * 0.08838834764831845f;
        const int s = colb + nb * 16, tq = rowb + r;
        if (s > tq || s < tq - (WIN_ - 1)) v = -INFINITY;
        sv[nb][r] = v;
        rmax[r] = fmaxf(rmax[r], v);
      }
    #pragma unroll
    for (int r = 0; r < 4; ++r)
      #pragma unroll
      for (int off = 1; off < 16; off <<= 1)
        rmax[r] = fmaxf(rmax[r], __shfl_xor(rmax[r], off, 64));
    float alpha[4], rsum[4];
    #pragma unroll
    for (int r = 0; r < 4; ++r) {
      const float mn = fmaxf(m_i[r], rmax[r]);
      alpha[r] = __expf(m_i[r] - mn);
      m_i[r] = mn;
      rsum[r] = 0.0f;
    }
    #pragma unroll
    for (int nb = 0; nb < 4; ++nb)
      #pragma unroll
      for (int r = 0; r < 4; ++r) {
        const float p = __expf(sv[nb][r] - m_i[r]);
        rsum[r] += p;
        Ps[(wave * 16 + quad * 4 + r) * 72 + nb * 16 + l16] = f2b(p);
      }
    #pragma unroll
    for (int r = 0; r < 4; ++r) {
      #pragma unroll
      for (int off = 1; off < 16; off <<= 1)
        rsum[r] += __shfl_xor(rsum[r], off, 64);
      l_i[r] = l_i[r] * alpha[r] + rsum[r];
    }
    #pragma unroll
    for (int nb = 0; nb < 8; ++nb)
      #pragma unroll
      for (int r = 0; r < 4; ++r)
        Oacc[nb][r] *= alpha[r];
    __syncthreads();

    #pragma unroll
    for (int ks = 0; ks < 2; ++ks) {
      const bf16x8 ap = *(const bf16x8*)&Ps[(wave * 16 + l16) * 72 + ks * 32 + quad * 8];
      #pragma unroll
      for (int nb = 0; nb < 8; ++nb) {
        const bf16x8 bv = *(const bf16x8*)&Vs[(nb * 16 + l16) * 72 + ks * 32 + quad * 8];
        Oacc[nb] = __builtin_amdgcn_mfma_f32_16x16x32_bf16(ap, bv, Oacc[nb], 0, 0, 0);
      }
    }
  }

  float rcp[4];
  #pragma unroll
  for (int r = 0; r < 4; ++r) rcp[r] = 1.0f / l_i[r];
  bf16* outp = attnb + ((long)(b * T_ + t0 + wave * 16 + quad * 4)) * EMB_ + h * HD_ + l16;
  #pragma unroll
  for (int nb = 0; nb < 8; ++nb)
    #pragma unroll
    for (int r = 0; r < 4; ++r)
      outp[(long)r * EMB_ + nb * 16] = f2b(Oacc[nb][r] * rcp[r]);
}

extern "C" void kernel_launch(void* const* d_in, const int* in_sizes, int n_in,
                              void* d_out, int out_size, void* d_ws, size_t ws_size,
                              hipStream_t stream)
{
  (void)in_sizes; (void)n_in; (void)out_size; (void)ws_size;
  const float* x    = (const float*)d_in[0];
  const float* wq   = (const float*)d_in[2];
  const float* wk   = (const float*)d_in[3];
  const float* wv   = (const float*)d_in[4];
  const float* wo   = (const float*)d_in[5];
  const float* sink = (const float*)d_in[6];
  const float* gw   = (const float*)d_in[7];
  const float* uw   = (const float*)d_in[8];
  const float* dw   = (const float*)d_in[9];
  const float* n1   = (const float*)d_in[10];
  const float* n2   = (const float*)d_in[11];

  char* base = (char*)d_ws;
  bf16*  hbuf  = (bf16*)base;                                   // 16,777,216
  char*  R1    = base + (size_t)16777216;                       // 67,108,864
  char*  R2    = R1   + (size_t)67108864;                       // 33,554,432
  bf16*  mact  = (bf16*)(R2 + (size_t)33554432);                // 67,108,864

  bf16* qkv   = (bf16*)R1;
  bf16* Qb    = (bf16*)(R1 + 25165824);
  bf16* Kb    = (bf16*)(R1 + 41943040);
  bf16* VTb   = (bf16*)(R1 + 46137344);
  bf16* attnb = (bf16*)R1;
  bf16* wqkvT = (bf16*)R2;
  bf16* woT   = (bf16*)(R2 + 12582912);
  bf16* Bcat  = (bf16*)R1;            // 16384 x 2048 bf16 (gate/up interleaved)
  bf16* downT = (bf16*)R2;
  float* x1   = (float*)d_out;

  const dim3 tb(32, 8);
  // ---- phase A: attention ----
  transpose_kernel<<<dim3( 64,  64), tb, 0, stream>>>(wq, wqkvT,                      EMB_, EMB_, 1, 0);
  transpose_kernel<<<dim3( 16,  64), tb, 0, stream>>>(wk, wqkvT + (size_t)2048*EMB_,  EMB_, 512, 1, 0);
  transpose_kernel<<<dim3( 16,  64), tb, 0, stream>>>(wv, wqkvT + (size_t)2560*EMB_,  EMB_, 512, 1, 0);
  transpose_kernel<<<dim3( 64,  64), tb, 0, stream>>>(wo, woT,                        EMB_, EMB_, 1, 0);

  rmsnorm_kernel<<<BT_, 256, 0, stream>>>(x, n1, hbuf);
  gemm256_kernel<0><<<dim3(QKVN_/256, BT_/128), 512, 0, stream>>>(hbuf, wqkvT, qkv, nullptr, BT_, QKVN_, EMB_);
  rope_kernel<<<dim3(T_, B_), 256, 0, stream>>>(qkv, Qb, Kb, VTb);
  attn_kernel<<<dim3(T_/64, B_*NH_), 256, 0, stream>>>(Qb, Kb, VTb, sink, attnb);
  gemm256_kernel<1><<<dim3(EMB_/256, BT_/128), 512, 0, stream>>>(attnb, woT, x1, x, BT_, EMB_, EMB_);

  // ---- phase B: MLP ----
  rmsnorm_kernel<<<BT_, 256, 0, stream>>>(x1, n2, hbuf);
  transpose_kernel<<<dim3(256,  64), tb, 0, stream>>>(gw, Bcat, EMB_, MLPD_, 2, 0);
  transpose_kernel<<<dim3(256,  64), tb, 0, stream>>>(uw, Bcat, EMB_, MLPD_, 2, 1);
  mlp_gateup256_kernel<<<dim3((2*MLPD_)/256, BT_/256), 512, 0, stream>>>(hbuf, Bcat, mact, BT_, 2*MLPD_, EMB_);
  transpose_kernel<<<dim3( 64, 256), tb, 0, stream>>>(dw, downT, MLPD_, EMB_, 1, 0);
  gemm256_kernel<1><<<dim3(EMB_/256, BT_/128), 512, 0, stream>>>(mact, downT, (float*)d_out, x1, BT_, EMB_, MLPD_);
}

// Round 5
// 961.307 us; speedup vs baseline: 1.1671x; 1.0011x over previous
//
#include <hip/hip_runtime.h>
#include <hip/hip_bf16.h>
#include <stdint.h>

#define B_    2
#define T_    2048
#define EMB_  2048
#define NH_   16
#define NKV_  4
#define HD_   128
#define MLPD_ 8192
#define WIN_  1024
#define BT_   (B_ * T_)     // 4096 rows
#define QKVN_ 3072          // NH*HD + NKV*HD + NKV*HD

typedef __bf16 bf16;
typedef __bf16 bf16x8 __attribute__((ext_vector_type(8)));
typedef float  f32x4  __attribute__((ext_vector_type(4)));

__device__ __forceinline__ bf16 f2b(float f) {
  __hip_bfloat16 h = __float2bfloat16(f);
  return *reinterpret_cast<bf16*>(&h);
}
__device__ __forceinline__ float b2f(bf16 b) {
  __hip_bfloat16 h = *reinterpret_cast<__hip_bfloat16*>(&b);
  return __bfloat162float(h);
}

__device__ __forceinline__ void load_lds16(const void* g, void* l) {
  __builtin_amdgcn_global_load_lds(
      (const __attribute__((address_space(1))) void*)g,
      (__attribute__((address_space(3))) void*)l, 16, 0, 0);
}

// ---------- transpose f32 [R][C] -> bf16 [remap(C)][R] ----------
__global__ __launch_bounds__(256) void transpose_kernel(
    const float* __restrict__ in, bf16* __restrict__ out, int R, int C,
    int rmul, int radd)
{
  __shared__ float tile[32][33];
  const int tx = threadIdx.x, ty = threadIdx.y;  // blockDim (32,8)
  const int c0 = blockIdx.x * 32, r0 = blockIdx.y * 32;
  #pragma unroll
  for (int i = 0; i < 32; i += 8)
    tile[ty + i][tx] = in[(long)(r0 + ty + i) * C + c0 + tx];
  __syncthreads();
  #pragma unroll
  for (int i = 0; i < 32; i += 8) {
    const int oc = c0 + ty + i;
    const int orow = (oc & 15) + (((oc >> 4) * rmul + radd) << 4);
    out[(long)orow * R + r0 + tx] = f2b(tile[tx][ty + i]);
  }
}

// ---------- RMSNorm: f32 row -> bf16 row ----------
__global__ __launch_bounds__(256) void rmsnorm_kernel(
    const float* __restrict__ x, const float* __restrict__ scale,
    bf16* __restrict__ out)
{
  const long row = blockIdx.x;
  const float* xr = x + row * EMB_;
  bf16* orow = out + row * EMB_;
  const float4 v0 = ((const float4*)xr)[threadIdx.x];
  const float4 v1 = ((const float4*)xr)[threadIdx.x + 256];
  float ss = v0.x*v0.x + v0.y*v0.y + v0.z*v0.z + v0.w*v0.w
           + v1.x*v1.x + v1.y*v1.y + v1.z*v1.z + v1.w*v1.w;
  #pragma unroll
  for (int off = 32; off >= 1; off >>= 1) ss += __shfl_xor(ss, off, 64);
  __shared__ float red[4];
  if ((threadIdx.x & 63) == 0) red[threadIdx.x >> 6] = ss;
  __syncthreads();
  const float tot = red[0] + red[1] + red[2] + red[3];
  const float rs = rsqrtf(tot * (1.0f / EMB_) + 1e-6f);
  const float4 s0 = ((const float4*)scale)[threadIdx.x];
  const float4 s1 = ((const float4*)scale)[threadIdx.x + 256];
  const int c0 = threadIdx.x * 4;
  orow[c0 + 0]    = f2b(v0.x * rs * (1.0f + s0.x));
  orow[c0 + 1]    = f2b(v0.y * rs * (1.0f + s0.y));
  orow[c0 + 2]    = f2b(v0.z * rs * (1.0f + s0.z));
  orow[c0 + 3]    = f2b(v0.w * rs * (1.0f + s0.w));
  orow[c0 + 1024] = f2b(v1.x * rs * (1.0f + s1.x));
  orow[c0 + 1025] = f2b(v1.y * rs * (1.0f + s1.y));
  orow[c0 + 1026] = f2b(v1.z * rs * (1.0f + s1.z));
  orow[c0 + 1027] = f2b(v1.w * rs * (1.0f + s1.w));
}

// ============ deep-pipelined 128M x 256N GEMM (3-buf, counted vmcnt) ============
#define DG_BAR()  do { asm volatile("" ::: "memory"); \
                       __builtin_amdgcn_s_barrier(); \
                       asm volatile("" ::: "memory"); } while (0)
#define DG_LGK0() do { asm volatile("s_waitcnt lgkmcnt(0)" ::: "memory"); \
                       __builtin_amdgcn_sched_barrier(0); } while (0)

#define DG_STAGE(TILE, BB) do { \
    _Pragma("unroll") \
    for (int j_ = 0; j_ < 6; ++j_) \
      load_lds16(srcp[j_] + (long)(TILE) * 64, smem + (BB) + dstoff[j_]); \
  } while (0)

#define DG_READA(BB) do { \
    _Pragma("unroll") \
    for (int mb_ = 0; mb_ < 4; ++mb_) { \
      const int rb_ = (wr * 64 + mb_ * 16 + l16) * 128; \
      afr[mb_][0] = *(const bf16x8*)(smem + (BB) + rb_ + koff0); \
      afr[mb_][1] = *(const bf16x8*)(smem + (BB) + rb_ + koff1); \
    } } while (0)

#define DG_READB(BB, NH) do { \
    _Pragma("unroll") \
    for (int nb_ = 0; nb_ < 2; ++nb_) { \
      const int rb_ = 16384 + (wc * 64 + (NH) * 32 + nb_ * 16 + l16) * 128; \
      bfr[nb_][0] = *(const bf16x8*)(smem + (BB) + rb_ + koff0); \
      bfr[nb_][1] = *(const bf16x8*)(smem + (BB) + rb_ + koff1); \
    } } while (0)

#define DG_MFMA(NH) do { \
    _Pragma("unroll") \
    for (int mb_ = 0; mb_ < 4; ++mb_) \
      _Pragma("unroll") \
      for (int nb_ = 0; nb_ < 2; ++nb_) { \
        f32x4* a_ = &acc[mb_][(NH) * 2 + nb_]; \
        *a_ = __builtin_amdgcn_mfma_f32_16x16x32_bf16(afr[mb_][0], bfr[nb_][0], *a_, 0, 0, 0); \
        *a_ = __builtin_amdgcn_mfma_f32_16x16x32_bf16(afr[mb_][1], bfr[nb_][1], *a_, 0, 0, 0); \
      } } while (0)

template <int EPI>
__global__ __launch_bounds__(512, 2) void gemm256_kernel(
    const bf16* __restrict__ A, const bf16* __restrict__ Bt,
    void* __restrict__ out, const float* __restrict__ res,
    int M, int N, int K)
{
  (void)M;
  __shared__ __align__(16) char smem[147456];   // 3 x 48 KiB rotating buffers
  const int tid  = threadIdx.x;
  const int wave = tid >> 6, lane = tid & 63;
  const int quad = lane >> 4, l16 = lane & 15;
  const int wr = wave >> 2, wc = wave & 3;        // 2M x 4N wave grid
  const int bm = blockIdx.y << 7, bn = blockIdx.x << 8;
  const int KT = K >> 6;

  const int koff0 = (quad * 16) ^ ((l16 & 7) << 4);
  const int koff1 = koff0 ^ 64;

  // staging: 48 chunks of 8 rows x 64 cols (1 KB); 6 per wave.
  const int srow = lane >> 3;
  const int scol = ((lane & 7) ^ srow) << 3;
  const bf16* srcp[6]; int dstoff[6];
  #pragma unroll
  for (int j = 0; j < 6; ++j) {
    const int c = 6 * wave + j;
    const int grow = (c < 16) ? (bm + c * 8 + srow) : (bn + (c - 16) * 8 + srow);
    const bf16* gbase = (c < 16) ? A : Bt;
    srcp[j] = gbase + (long)grow * K + scol;
    dstoff[j] = c * 1024;
  }

  f32x4 acc[4][4] = {};
  bf16x8 afr[4][2];
  bf16x8 bfr[2][2];

  int base0 = 0, base1 = 49152, base2 = 98304;

  // prologue: tiles 0,1 in flight; hard drain once (cold-start safety)
  DG_STAGE(0, base0);
  DG_STAGE(1, base1);
  asm volatile("s_waitcnt vmcnt(0)" ::: "memory");
  DG_BAR();

  #pragma unroll 1
  for (int t = 0; t < KT; ++t) {
    // p0: issue batch t+2 -> base2; compute NH0 of tile t (base0 ready)
    if (t + 2 < KT) DG_STAGE(t + 2, base2);
    DG_READA(base0); DG_READB(base0, 0);
    DG_BAR(); DG_LGK0();
    __builtin_amdgcn_s_setprio(1); DG_MFMA(0); __builtin_amdgcn_s_setprio(0);
    DG_BAR();
    // p1: compute NH1; retire batch t+1 (t+2's 6 loads stay in flight)
    DG_READB(base0, 1);
    DG_BAR(); DG_LGK0();
    __builtin_amdgcn_s_setprio(1); DG_MFMA(1); __builtin_amdgcn_s_setprio(0);
    if (t + 2 < KT) { asm volatile("s_waitcnt vmcnt(6)" ::: "memory"); }
    else            { asm volatile("s_waitcnt vmcnt(0)" ::: "memory"); }
    DG_BAR();
    const int r_ = base0; base0 = base1; base1 = base2; base2 = r_;
  }

  const int crow = bm + wr * 64 + (quad << 2);
  const int ccol = bn + wc * 64 + l16;
  #pragma unroll
  for (int mb = 0; mb < 4; ++mb)
    #pragma unroll
    for (int nb = 0; nb < 4; ++nb)
      #pragma unroll
      for (int r = 0; r < 4; ++r) {
        const long idx = (long)(crow + mb * 16 + r) * N + (ccol + nb * 16);
        const float v = acc[mb][nb][r];
        if (EPI == 0) {
          ((bf16*)out)[idx] = f2b(v);
        } else {
          ((float*)out)[idx] = v + res[idx];
        }
      }
}

// ================== Fused gate+up 256x256 8-phase GEMM ==================
// v2: counted-vmcnt pipeline (T4). Stages at p3/p7 targeting t+2/t+3;
// retire with vmcnt(8) (next stage's 8 loads stay in flight across barriers).
// Never drains to 0 in steady state; 4-phase issue->retire window per tile.
#define GU_BAR()  do { asm volatile("" ::: "memory"); \
                       __builtin_amdgcn_s_barrier(); \
                       asm volatile("" ::: "memory"); } while (0)
#define GU_LGK0() do { asm volatile("s_waitcnt lgkmcnt(0)" ::: "memory"); \
                       __builtin_amdgcn_sched_barrier(0); } while (0)

#define GU_STAGE(TILE, BB) do { \
    _Pragma("unroll") \
    for (int j_ = 0; j_ < 8; ++j_) \
      load_lds16(srcp[j_] + (long)(TILE) * 64, smem + (BB) + dstoff[j_]); \
  } while (0)

#define GU_READA(BB, MH) do { \
    const char* ab_ = smem + (BB) + wroff; \
    _Pragma("unroll") \
    for (int mb_ = 0; mb_ < 4; ++mb_) { \
      const int rb_ = ((MH) * 64 + mb_ * 16 + l16) * 128; \
      afr[mb_][0] = *(const bf16x8*)(ab_ + rb_ + koff0); \
      afr[mb_][1] = *(const bf16x8*)(ab_ + rb_ + koff1); \
    } } while (0)

#define GU_READB(BB, NH) do { \
    const char* bb_ = smem + (BB) + 32768 + bhoff; \
    _Pragma("unroll") \
    for (int nb_ = 0; nb_ < 2; ++nb_) { \
      const int rb_ = (brow0 + (NH) * 32 + nb_ * 16) * 128; \
      bfr[NH][nb_][0] = *(const bf16x8*)(bb_ + rb_ + koff0); \
      bfr[NH][nb_][1] = *(const bf16x8*)(bb_ + rb_ + koff1); \
    } } while (0)

#define GU_MFMAQ(MH, NH) do { \
    _Pragma("unroll") \
    for (int mb_ = 0; mb_ < 4; ++mb_) \
      _Pragma("unroll") \
      for (int nb_ = 0; nb_ < 2; ++nb_) { \
        f32x4* a_ = &acc[(MH) * 4 + mb_][(NH) * 2 + nb_]; \
        *a_ = __builtin_amdgcn_mfma_f32_16x16x32_bf16(afr[mb_][0], bfr[NH][nb_][0], *a_, 0, 0, 0); \
        *a_ = __builtin_amdgcn_mfma_f32_16x16x32_bf16(afr[mb_][1], bfr[NH][nb_][1], *a_, 0, 0, 0); \
      } } while (0)

__global__ __launch_bounds__(512, 2) void mlp_gateup256_kernel(
    const bf16* __restrict__ A, const bf16* __restrict__ Bc,
    bf16* __restrict__ out, int M, int Ncat, int K)
{
  (void)M;
  __shared__ __align__(16) char smem[131072];
  const int tid  = threadIdx.x;
  const int wave = tid >> 6, lane = tid & 63;
  const int quad = lane >> 4, l16 = lane & 15;
  const int wr = wave >> 2, wc = wave & 3;
  const int bm = blockIdx.y << 8, bn = blockIdx.x << 8;
  const int KT = K >> 6;

  const int koff0 = (quad * 16) ^ ((l16 & 7) << 4);
  const int koff1 = koff0 ^ 64;
  const int wroff = wr * 16384;
  const int bhoff = (wc >> 1) * 16384;
  const int brow0 = (wc & 1) * 64 + l16;

  const int srow = lane >> 3;
  const int scol = ((lane & 7) ^ srow) << 3;
  const bf16* srcp[8]; int dstoff[8];
  #pragma unroll
  for (int op = 0; op < 2; ++op)
    #pragma unroll
    for (int h = 0; h < 2; ++h)
      #pragma unroll
      for (int g = 0; g < 2; ++g) {
        const int j = op * 4 + h * 2 + g;
        const int grow = (op ? bn : bm) + h * 128 + g * 64 + wave * 8 + srow;
        srcp[j] = (op ? Bc : A) + (long)grow * K + scol;
        dstoff[j] = op * 32768 + h * 16384 + g * 8192 + wave * 1024;
      }

  f32x4 acc[8][4] = {};
  bf16x8 afr[4][2];
  bf16x8 bfr[2][2][2];

  // prologue: both buffers staged; retire tile 0 only (tile 1 stays in flight)
  GU_STAGE(0, 0);
  GU_STAGE(1, 65536);
  asm volatile("s_waitcnt vmcnt(8)" ::: "memory");
  GU_BAR();

  #pragma unroll 1
  for (int t = 0; t < KT; t += 2) {
    // p0: tile t (buf0) Q(0,0)
    GU_READA(0, 0); GU_READB(0, 0);
    GU_BAR(); GU_LGK0();
    __builtin_amdgcn_s_setprio(1); GU_MFMAQ(0, 0); __builtin_amdgcn_s_setprio(0);
    GU_BAR();
    // p1: Q(0,1)
    GU_READB(0, 1);
    GU_BAR(); GU_LGK0();
    __builtin_amdgcn_s_setprio(1); GU_MFMAQ(0, 1); __builtin_amdgcn_s_setprio(0);
    GU_BAR();
    // p2: Q(1,1)  (last buf0 reads retired at this phase's close)
    GU_READA(0, 1);
    GU_BAR(); GU_LGK0();
    __builtin_amdgcn_s_setprio(1); GU_MFMAQ(1, 1); __builtin_amdgcn_s_setprio(0);
    GU_BAR();
    // p3: stage t+2 -> buf0 (free); Q(1,0) from regs; retire t+1 via vmcnt(8)
    if (t + 2 < KT) {
      GU_STAGE(t + 2, 0);
      __builtin_amdgcn_s_setprio(1); GU_MFMAQ(1, 0); __builtin_amdgcn_s_setprio(0);
      asm volatile("s_waitcnt vmcnt(8)" ::: "memory");
    } else {
      __builtin_amdgcn_s_setprio(1); GU_MFMAQ(1, 0); __builtin_amdgcn_s_setprio(0);
      asm volatile("s_waitcnt vmcnt(0)" ::: "memory");
    }
    GU_BAR();
    // p4: tile t+1 (buf1) Q(0,0)
    GU_READA(65536, 0); GU_READB(65536, 0);
    GU_BAR(); GU_LGK0();
    __builtin_amdgcn_s_setprio(1); GU_MFMAQ(0, 0); __builtin_amdgcn_s_setprio(0);
    GU_BAR();
    // p5: Q(0,1)
    GU_READB(65536, 1);
    GU_BAR(); GU_LGK0();
    __builtin_amdgcn_s_setprio(1); GU_MFMAQ(0, 1); __builtin_amdgcn_s_setprio(0);
    GU_BAR();
    // p6: Q(1,1)
    GU_READA(65536, 1);
    GU_BAR(); GU_LGK0();
    __builtin_amdgcn_s_setprio(1); GU_MFMAQ(1, 1); __builtin_amdgcn_s_setprio(0);
    GU_BAR();
    // p7: stage t+3 -> buf1 (free); Q(1,0); retire t+2 via vmcnt(8)
    if (t + 3 < KT) {
      GU_STAGE(t + 3, 65536);
      __builtin_amdgcn_s_setprio(1); GU_MFMAQ(1, 0); __builtin_amdgcn_s_setprio(0);
      asm volatile("s_waitcnt vmcnt(8)" ::: "memory");
    } else {
      __builtin_amdgcn_s_setprio(1); GU_MFMAQ(1, 0); __builtin_amdgcn_s_setprio(0);
      asm volatile("s_waitcnt vmcnt(0)" ::: "memory");
    }
    GU_BAR();
  }

  // epilogue: fragment pair (nb even = gate, nb odd = up) -> silu(g)*u
  const long NO = Ncat >> 1;
  const int orow0 = bm + wr * 128 + (quad << 2);
  const int ocol  = (bn >> 1) + wc * 32 + l16;
  #pragma unroll
  for (int ma = 0; ma < 8; ++ma)
    #pragma unroll
    for (int nh = 0; nh < 2; ++nh)
      #pragma unroll
      for (int r = 0; r < 4; ++r) {
        const float g = acc[ma][nh * 2][r];
        const float u = acc[ma][nh * 2 + 1][r];
        out[(long)(orow0 + ma * 16 + r) * NO + ocol + nh * 16] =
            f2b(g / (1.0f + __expf(-g)) * u);
      }
}

// ---------- RoPE + layout ----------
__global__ __launch_bounds__(256) void rope_kernel(
    const bf16* __restrict__ qkv, bf16* __restrict__ Q,
    bf16* __restrict__ K, bf16* __restrict__ VT)
{
  const int t = blockIdx.x, b = blockIdx.y;
  const bf16* row = qkv + (long)(b * T_ + t) * QKVN_;
  const float tf = (float)t;
  for (int idx = threadIdx.x; idx < NH_ * HD_; idx += 256) {
    const int head = idx >> 7, hd = idx & 127;
    const float v = b2f(row[idx]);
    float o;
    if (hd < 64) {
      const int j = hd & 31;
      const float ang = tf * expf(-(float)j * 0.28782313662425574f);
      const float sn = sinf(ang), cs = cosf(ang);
      o = (hd < 32) ? (v * cs - b2f(row[idx + 32]) * sn)
                    : (v * cs + b2f(row[idx - 32]) * sn);
    } else o = v;
    Q[((long)(b * NH_ + head) * T_ + t) * HD_ + hd] = f2b(o);
  }
  for (int idx = threadIdx.x; idx < NKV_ * HD_; idx += 256) {
    const int kv = idx >> 7, hd = idx & 127;
    const float v = b2f(row[NH_ * HD_ + idx]);
    float o;
    if (hd < 64) {
      const int j = hd & 31;
      const float ang = tf * expf(-(float)j * 0.28782313662425574f);
      const float sn = sinf(ang), cs = cosf(ang);
      o = (hd < 32) ? (v * cs - b2f(row[NH_ * HD_ + idx + 32]) * sn)
                    : (v * cs + b2f(row[NH_ * HD_ + idx - 32]) * sn);
    } else o = v;
    K[((long)(b * NKV_ + kv) * T_ + t) * HD_ + hd] = f2b(o);
  }
  for (int idx = threadIdx.x; idx < NKV_ * HD_; idx += 256) {
    const int kv = idx >> 7, vd = idx & 127;
    VT[((long)(b * NKV_ + kv) * HD_ + vd) * T_ + t] = row[(NH_ + NKV_) * HD_ + idx];
  }
}

// ---------- Flash attention ----------
__global__ __launch_bounds__(256) void attn_kernel(
    const bf16* __restrict__ Q, const bf16* __restrict__ Kg,
    const bf16* __restrict__ VTg, const float* __restrict__ sink,
    bf16* __restrict__ attnb)
{
  __shared__ __align__(16) bf16 Qs[64 * 136];
  __shared__ __align__(16) bf16 Ks[64 * 136];
  __shared__ __align__(16) bf16 Vs[128 * 72];
  __shared__ __align__(16) bf16 Ps[64 * 72];

  const int qt = blockIdx.x;
  const int bh = blockIdx.y;
  const int b = bh >> 4, h = bh & 15;
  const int kvh = h >> 2;
  const int t0 = qt * 64;
  const int tid = threadIdx.x;
  const int wave = tid >> 6, lane = tid & 63;
  const int quad = lane >> 4, l16 = lane & 15;

  const bf16* Qp = Q + ((long)(b * NH_ + h) * T_ + t0) * HD_;
  #pragma unroll
  for (int c = tid; c < 1024; c += 256) {
    const int r = c >> 4, cc = (c & 15) << 3;
    *(uint4*)&Qs[r * 136 + cc] = *(const uint4*)&Qp[r * HD_ + cc];
  }

  float m_i[4], l_i[4];
  const float sb = sink[h];
  #pragma unroll
  for (int r = 0; r < 4; ++r) { m_i[r] = sb; l_i[r] = 1.0f; }
  f32x4 Oacc[8] = {};

  const int st_lo = (qt > 16) ? (qt - 16) : 0;
  for (int st = st_lo; st <= qt; ++st) {
    const int s0 = st * 64;
    __syncthreads();
    const bf16* Kp = Kg + ((long)(b * NKV_ + kvh) * T_ + s0) * HD_;
    #pragma unroll
    for (int c = tid; c < 1024; c += 256) {
      const int r = c >> 4, cc = (c & 15) << 3;
      *(uint4*)&Ks[r * 136 + cc] = *(const uint4*)&Kp[r * HD_ + cc];
    }
    const bf16* Vp = VTg + (long)(b * NKV_ + kvh) * HD_ * T_ + s0;
    #pragma unroll
    for (int c = tid; c < 1024; c += 256) {
      const int r = c >> 3, cc = (c & 7) << 3;
      *(uint4*)&Vs[r * 72 + cc] = *(const uint4*)&Vp[(long)r * T_ + cc];
    }
    __syncthreads();

    f32x4 sacc[4] = {};
    #pragma unroll
    for (int kb = 0; kb < 4; ++kb) {
      const bf16x8 aq = *(const bf16x8*)&Qs[(wave * 16 + l16) * 136 + kb * 32 + quad * 8];
      #pragma unroll
      for (int nb = 0; nb < 4; ++nb) {
        const bf16x8 bk = *(const bf16x8*)&Ks[(nb * 16 + l16) * 136 + kb * 32 + quad * 8];
        sacc[nb] = __builtin_amdgcn_mfma_f32_16x16x32_bf16(aq, bk, sacc[nb], 0, 0, 0);
      }
    }

    float sv[4][4];
    float rmax[4] = {-INFINITY, -INFINITY, -INFINITY, -INFINITY};
    const int colb = s0 + l16;
    const int rowb = t0 + wave * 16 + quad * 4;
    #pragma unroll
    for (int nb = 0; nb < 4; ++nb)
      #pragma unroll
      for (int r = 0; r < 4; ++r) {
        float v = sacc[nb][r] * 0.08838834764831845f;
        const int s = colb + nb * 16, tq = rowb + r;
        if (s > tq || s < tq - (WIN_ - 1)) v = -INFINITY;
        sv[nb][r] = v;
        rmax[r] = fmaxf(rmax[r], v);
      }
    #pragma unroll
    for (int r = 0; r < 4; ++r)
      #pragma unroll
      for (int off = 1; off < 16; off <<= 1)
        rmax[r] = fmaxf(rmax[r], __shfl_xor(rmax[r], off, 64));
    float alpha[4], rsum[4];
    #pragma unroll
    for (int r = 0; r < 4; ++r) {
      const float mn = fmaxf(m_i[r], rmax[r]);
      alpha[r] = __expf(m_i[r] - mn);
      m_i[r] = mn;
      rsum[r] = 0.0f;
    }
    #pragma unroll
    for (int nb = 0; nb < 4; ++nb)
      #pragma unroll
      for (int r = 0; r < 4; ++r) {
        const float p = __expf(sv[nb][r] - m_i[r]);
        rsum[r] += p;
        Ps[(wave * 16 + quad * 4 + r) * 72 + nb * 16 + l16] = f2b(p);
      }
    #pragma unroll
    for (int r = 0; r < 4; ++r) {
      #pragma unroll
      for (int off = 1; off < 16; off <<= 1)
        rsum[r] += __shfl_xor(rsum[r], off, 64);
      l_i[r] = l_i[r] * alpha[r] + rsum[r];
    }
    #pragma unroll
    for (int nb = 0; nb < 8; ++nb)
      #pragma unroll
      for (int r = 0; r < 4; ++r)
        Oacc[nb][r] *= alpha[r];
    __syncthreads();

    #pragma unroll
    for (int ks = 0; ks < 2; ++ks) {
      const bf16x8 ap = *(const bf16x8*)&Ps[(wave * 16 + l16) * 72 + ks * 32 + quad * 8];
      #pragma unroll
      for (int nb = 0; nb < 8; ++nb) {
        const bf16x8 bv = *(const bf16x8*)&Vs[(nb * 16 + l16) * 72 + ks * 32 + quad * 8];
        Oacc[nb] = __builtin_amdgcn_mfma_f32_16x16x32_bf16(ap, bv, Oacc[nb], 0, 0, 0);
      }
    }
  }

  float rcp[4];
  #pragma unroll
  for (int r = 0; r < 4; ++r) rcp[r] = 1.0f / l_i[r];
  bf16* outp = attnb + ((long)(b * T_ + t0 + wave * 16 + quad * 4)) * EMB_ + h * HD_ + l16;
  #pragma unroll
  for (int nb = 0; nb < 8; ++nb)
    #pragma unroll
    for (int r = 0; r < 4; ++r)
      outp[(long)r * EMB_ + nb * 16] = f2b(Oacc[nb][r] * rcp[r]);
}

extern "C" void kernel_launch(void* const* d_in, const int* in_sizes, int n_in,
                              void* d_out, int out_size, void* d_ws, size_t ws_size,
                              hipStream_t stream)
{
  (void)in_sizes; (void)n_in; (void)out_size; (void)ws_size;
  const float* x    = (const float*)d_in[0];
  const float* wq   = (const float*)d_in[2];
  const float* wk   = (const float*)d_in[3];
  const float* wv   = (const float*)d_in[4];
  const float* wo   = (const float*)d_in[5];
  const float* sink = (const float*)d_in[6];
  const float* gw   = (const float*)d_in[7];
  const float* uw   = (const float*)d_in[8];
  const float* dw   = (const float*)d_in[9];
  const float* n1   = (const float*)d_in[10];
  const float* n2   = (const float*)d_in[11];

  char* base = (char*)d_ws;
  bf16*  hbuf  = (bf16*)base;                                   // 16,777,216
  char*  R1    = base + (size_t)16777216;                       // 67,108,864
  char*  R2    = R1   + (size_t)67108864;                       // 33,554,432
  bf16*  mact  = (bf16*)(R2 + (size_t)33554432);                // 67,108,864

  bf16* qkv   = (bf16*)R1;
  bf16* Qb    = (bf16*)(R1 + 25165824);
  bf16* Kb    = (bf16*)(R1 + 41943040);
  bf16* VTb   = (bf16*)(R1 + 46137344);
  bf16* attnb = (bf16*)R1;
  bf16* wqkvT = (bf16*)R2;
  bf16* woT   = (bf16*)(R2 + 12582912);
  bf16* Bcat  = (bf16*)R1;            // 16384 x 2048 bf16 (gate/up interleaved)
  bf16* downT = (bf16*)R2;
  float* x1   = (float*)d_out;

  const dim3 tb(32, 8);
  // ---- phase A: attention ----
  transpose_kernel<<<dim3( 64,  64), tb, 0, stream>>>(wq, wqkvT,                      EMB_, EMB_, 1, 0);
  transpose_kernel<<<dim3( 16,  64), tb, 0, stream>>>(wk, wqkvT + (size_t)2048*EMB_,  EMB_, 512, 1, 0);
  transpose_kernel<<<dim3( 16,  64), tb, 0, stream>>>(wv, wqkvT + (size_t)2560*EMB_,  EMB_, 512, 1, 0);
  transpose_kernel<<<dim3( 64,  64), tb, 0, stream>>>(wo, woT,                        EMB_, EMB_, 1, 0);

  rmsnorm_kernel<<<BT_, 256, 0, stream>>>(x, n1, hbuf);
  gemm256_kernel<0><<<dim3(QKVN_/256, BT_/128), 512, 0, stream>>>(hbuf, wqkvT, qkv, nullptr, BT_, QKVN_, EMB_);
  rope_kernel<<<dim3(T_, B_), 256, 0, stream>>>(qkv, Qb, Kb, VTb);
  attn_kernel<<<dim3(T_/64, B_*NH_), 256, 0, stream>>>(Qb, Kb, VTb, sink, attnb);
  gemm256_kernel<1><<<dim3(EMB_/256, BT_/128), 512, 0, stream>>>(attnb, woT, x1, x, BT_, EMB_, EMB_);

  // ---- phase B: MLP ----
  rmsnorm_kernel<<<BT_, 256, 0, stream>>>(x1, n2, hbuf);
  transpose_kernel<<<dim3(256,  64), tb, 0, stream>>>(gw, Bcat, EMB_, MLPD_, 2, 0);
  transpose_kernel<<<dim3(256,  64), tb, 0, stream>>>(uw, Bcat, EMB_, MLPD_, 2, 1);
  mlp_gateup256_kernel<<<dim3((2*MLPD_)/256, BT_/256), 512, 0, stream>>>(hbuf, Bcat, mact, BT_, 2*MLPD_, EMB_);
  transpose_kernel<<<dim3( 64, 256), tb, 0, stream>>>(dw, downT, MLPD_, EMB_, 1, 0);
  gemm256_kernel<1><<<dim3(EMB_/256, BT_/128), 512, 0, stream>>>(mact, downT, (float*)d_out, x1, BT_, EMB_, MLPD_);
}

// Round 6
// 932.811 us; speedup vs baseline: 1.2028x; 1.0305x over previous
//
#include <hip/hip_runtime.h>
#include <hip/hip_bf16.h>
#include <stdint.h>

#define B_    2
#define T_    2048
#define EMB_  2048
#define NH_   16
#define NKV_  4
#define HD_   128
#define MLPD_ 8192
#define WIN_  1024
#define BT_   (B_ * T_)     // 4096 rows
#define QKVN_ 3072          // NH*HD + NKV*HD + NKV*HD

typedef __bf16 bf16;
typedef __bf16 bf16x8 __attribute__((ext_vector_type(8)));
typedef float  f32x4  __attribute__((ext_vector_type(4)));

__device__ __forceinline__ bf16 f2b(float f) {
  __hip_bfloat16 h = __float2bfloat16(f);
  return *reinterpret_cast<bf16*>(&h);
}
__device__ __forceinline__ float b2f(bf16 b) {
  __hip_bfloat16 h = *reinterpret_cast<__hip_bfloat16*>(&b);
  return __bfloat162float(h);
}

__device__ __forceinline__ void load_lds16(const void* g, void* l) {
  __builtin_amdgcn_global_load_lds(
      (const __attribute__((address_space(1))) void*)g,
      (__attribute__((address_space(3))) void*)l, 16, 0, 0);
}

// ---------- transpose f32 [R][C] -> bf16 [remap(C)][R] ----------
__global__ __launch_bounds__(256) void transpose_kernel(
    const float* __restrict__ in, bf16* __restrict__ out, int R, int C,
    int rmul, int radd)
{
  __shared__ float tile[32][33];
  const int tx = threadIdx.x, ty = threadIdx.y;  // blockDim (32,8)
  const int c0 = blockIdx.x * 32, r0 = blockIdx.y * 32;
  #pragma unroll
  for (int i = 0; i < 32; i += 8)
    tile[ty + i][tx] = in[(long)(r0 + ty + i) * C + c0 + tx];
  __syncthreads();
  #pragma unroll
  for (int i = 0; i < 32; i += 8) {
    const int oc = c0 + ty + i;
    const int orow = (oc & 15) + (((oc >> 4) * rmul + radd) << 4);
    out[(long)orow * R + r0 + tx] = f2b(tile[tx][ty + i]);
  }
}

// ---------- RMSNorm: f32 row -> bf16 row ----------
__global__ __launch_bounds__(256) void rmsnorm_kernel(
    const float* __restrict__ x, const float* __restrict__ scale,
    bf16* __restrict__ out)
{
  const long row = blockIdx.x;
  const float* xr = x + row * EMB_;
  bf16* orow = out + row * EMB_;
  const float4 v0 = ((const float4*)xr)[threadIdx.x];
  const float4 v1 = ((const float4*)xr)[threadIdx.x + 256];
  float ss = v0.x*v0.x + v0.y*v0.y + v0.z*v0.z + v0.w*v0.w
           + v1.x*v1.x + v1.y*v1.y + v1.z*v1.z + v1.w*v1.w;
  #pragma unroll
  for (int off = 32; off >= 1; off >>= 1) ss += __shfl_xor(ss, off, 64);
  __shared__ float red[4];
  if ((threadIdx.x & 63) == 0) red[threadIdx.x >> 6] = ss;
  __syncthreads();
  const float tot = red[0] + red[1] + red[2] + red[3];
  const float rs = rsqrtf(tot * (1.0f / EMB_) + 1e-6f);
  const float4 s0 = ((const float4*)scale)[threadIdx.x];
  const float4 s1 = ((const float4*)scale)[threadIdx.x + 256];
  const int c0 = threadIdx.x * 4;
  orow[c0 + 0]    = f2b(v0.x * rs * (1.0f + s0.x));
  orow[c0 + 1]    = f2b(v0.y * rs * (1.0f + s0.y));
  orow[c0 + 2]    = f2b(v0.z * rs * (1.0f + s0.z));
  orow[c0 + 3]    = f2b(v0.w * rs * (1.0f + s0.w));
  orow[c0 + 1024] = f2b(v1.x * rs * (1.0f + s1.x));
  orow[c0 + 1025] = f2b(v1.y * rs * (1.0f + s1.y));
  orow[c0 + 1026] = f2b(v1.z * rs * (1.0f + s1.z));
  orow[c0 + 1027] = f2b(v1.w * rs * (1.0f + s1.w));
}

// ============ deep-pipelined 128M x 256N GEMM (3-buf, counted vmcnt) ============
#define DG_BAR()  do { asm volatile("" ::: "memory"); \
                       __builtin_amdgcn_s_barrier(); \
                       asm volatile("" ::: "memory"); } while (0)
#define DG_LGK0() do { asm volatile("s_waitcnt lgkmcnt(0)" ::: "memory"); \
                       __builtin_amdgcn_sched_barrier(0); } while (0)

#define DG_STAGE(TILE, BB) do { \
    _Pragma("unroll") \
    for (int j_ = 0; j_ < 6; ++j_) \
      load_lds16(srcp[j_] + (long)(TILE) * 64, smem + (BB) + dstoff[j_]); \
  } while (0)

#define DG_READA(BB) do { \
    _Pragma("unroll") \
    for (int mb_ = 0; mb_ < 4; ++mb_) { \
      const int rb_ = (wr * 64 + mb_ * 16 + l16) * 128; \
      afr[mb_][0] = *(const bf16x8*)(smem + (BB) + rb_ + koff0); \
      afr[mb_][1] = *(const bf16x8*)(smem + (BB) + rb_ + koff1); \
    } } while (0)

#define DG_READB(BB, NH) do { \
    _Pragma("unroll") \
    for (int nb_ = 0; nb_ < 2; ++nb_) { \
      const int rb_ = 16384 + (wc * 64 + (NH) * 32 + nb_ * 16 + l16) * 128; \
      bfr[nb_][0] = *(const bf16x8*)(smem + (BB) + rb_ + koff0); \
      bfr[nb_][1] = *(const bf16x8*)(smem + (BB) + rb_ + koff1); \
    } } while (0)

#define DG_MFMA(NH) do { \
    _Pragma("unroll") \
    for (int mb_ = 0; mb_ < 4; ++mb_) \
      _Pragma("unroll") \
      for (int nb_ = 0; nb_ < 2; ++nb_) { \
        f32x4* a_ = &acc[mb_][(NH) * 2 + nb_]; \
        *a_ = __builtin_amdgcn_mfma_f32_16x16x32_bf16(afr[mb_][0], bfr[nb_][0], *a_, 0, 0, 0); \
        *a_ = __builtin_amdgcn_mfma_f32_16x16x32_bf16(afr[mb_][1], bfr[nb_][1], *a_, 0, 0, 0); \
      } } while (0)

template <int EPI>
__global__ __launch_bounds__(512, 2) void gemm256_kernel(
    const bf16* __restrict__ A, const bf16* __restrict__ Bt,
    void* __restrict__ out, const float* __restrict__ res,
    int M, int N, int K)
{
  (void)M;
  __shared__ __align__(16) char smem[147456];   // 3 x 48 KiB rotating buffers
  const int tid  = threadIdx.x;
  const int wave = tid >> 6, lane = tid & 63;
  const int quad = lane >> 4, l16 = lane & 15;
  const int wr = wave >> 2, wc = wave & 3;        // 2M x 4N wave grid
  const int bm = blockIdx.y << 7, bn = blockIdx.x << 8;
  const int KT = K >> 6;

  const int koff0 = (quad * 16) ^ ((l16 & 7) << 4);
  const int koff1 = koff0 ^ 64;

  // staging: 48 chunks of 8 rows x 64 cols (1 KB); 6 per wave.
  const int srow = lane >> 3;
  const int scol = ((lane & 7) ^ srow) << 3;
  const bf16* srcp[6]; int dstoff[6];
  #pragma unroll
  for (int j = 0; j < 6; ++j) {
    const int c = 6 * wave + j;
    const int grow = (c < 16) ? (bm + c * 8 + srow) : (bn + (c - 16) * 8 + srow);
    const bf16* gbase = (c < 16) ? A : Bt;
    srcp[j] = gbase + (long)grow * K + scol;
    dstoff[j] = c * 1024;
  }

  f32x4 acc[4][4] = {};
  bf16x8 afr[4][2];
  bf16x8 bfr[2][2];

  int base0 = 0, base1 = 49152, base2 = 98304;

  // prologue: tiles 0,1 in flight; hard drain once (cold-start safety)
  DG_STAGE(0, base0);
  DG_STAGE(1, base1);
  asm volatile("s_waitcnt vmcnt(0)" ::: "memory");
  DG_BAR();

  #pragma unroll 1
  for (int t = 0; t < KT; ++t) {
    // p0: issue batch t+2 -> base2; compute NH0 of tile t (base0 ready)
    if (t + 2 < KT) DG_STAGE(t + 2, base2);
    DG_READA(base0); DG_READB(base0, 0);
    DG_BAR(); DG_LGK0();
    __builtin_amdgcn_s_setprio(1); DG_MFMA(0); __builtin_amdgcn_s_setprio(0);
    DG_BAR();
    // p1: compute NH1; retire batch t+1 (t+2's 6 loads stay in flight)
    DG_READB(base0, 1);
    DG_BAR(); DG_LGK0();
    __builtin_amdgcn_s_setprio(1); DG_MFMA(1); __builtin_amdgcn_s_setprio(0);
    if (t + 2 < KT) { asm volatile("s_waitcnt vmcnt(6)" ::: "memory"); }
    else            { asm volatile("s_waitcnt vmcnt(0)" ::: "memory"); }
    DG_BAR();
    const int r_ = base0; base0 = base1; base1 = base2; base2 = r_;
  }

  const int crow = bm + wr * 64 + (quad << 2);
  const int ccol = bn + wc * 64 + l16;
  #pragma unroll
  for (int mb = 0; mb < 4; ++mb)
    #pragma unroll
    for (int nb = 0; nb < 4; ++nb)
      #pragma unroll
      for (int r = 0; r < 4; ++r) {
        const long idx = (long)(crow + mb * 16 + r) * N + (ccol + nb * 16);
        const float v = acc[mb][nb][r];
        if (EPI == 0) {
          ((bf16*)out)[idx] = f2b(v);
        } else {
          ((float*)out)[idx] = v + res[idx];
        }
      }
}

// ================== Fused gate+up 256x256 GEMM ==================
// v3: AITER-style K-loop — 1 barrier + 1 vmcnt(0) per K-tile, intra-tile
// software-pipelined ds_reads with counted lgkmcnt so LDS reads overlap
// MFMA (fixes the phase-serialization measured at 45% MfmaUtil).
// Cross-wave safety: each wave COMPLETES all its reads of a buffer (data
// deps force lgkm retirement) before the tile-end barrier -> restaging
// that buffer next tile is write-after-read safe.
#define GU_BAR()  do { asm volatile("" ::: "memory"); \
                       __builtin_amdgcn_s_barrier(); \
                       asm volatile("" ::: "memory"); } while (0)
#define GU_LGK(N) do { asm volatile("s_waitcnt lgkmcnt(" #N ")" ::: "memory"); \
                       __builtin_amdgcn_sched_barrier(0); } while (0)
#define GU_VMC0() asm volatile("s_waitcnt vmcnt(0)" ::: "memory")

#define GU_STAGE(TILE, BB) do { \
    _Pragma("unroll") \
    for (int j_ = 0; j_ < 8; ++j_) \
      load_lds16(srcp[j_] + (long)(TILE) * 64, smem + (BB) + dstoff[j_]); \
  } while (0)

#define GU_READA(BB, MH) do { \
    const char* ab_ = smem + (BB) + wroff; \
    _Pragma("unroll") \
    for (int mb_ = 0; mb_ < 4; ++mb_) { \
      const int rb_ = ((MH) * 64 + mb_ * 16 + l16) * 128; \
      afr[mb_][0] = *(const bf16x8*)(ab_ + rb_ + koff0); \
      afr[mb_][1] = *(const bf16x8*)(ab_ + rb_ + koff1); \
    } } while (0)

#define GU_READB(BB, NH) do { \
    const char* bb_ = smem + (BB) + 32768 + bhoff; \
    _Pragma("unroll") \
    for (int nb_ = 0; nb_ < 2; ++nb_) { \
      const int rb_ = (brow0 + (NH) * 32 + nb_ * 16) * 128; \
      bfr[NH][nb_][0] = *(const bf16x8*)(bb_ + rb_ + koff0); \
      bfr[NH][nb_][1] = *(const bf16x8*)(bb_ + rb_ + koff1); \
    } } while (0)

#define GU_MFMAQ(MH, NH) do { \
    _Pragma("unroll") \
    for (int mb_ = 0; mb_ < 4; ++mb_) \
      _Pragma("unroll") \
      for (int nb_ = 0; nb_ < 2; ++nb_) { \
        f32x4* a_ = &acc[(MH) * 4 + mb_][(NH) * 2 + nb_]; \
        *a_ = __builtin_amdgcn_mfma_f32_16x16x32_bf16(afr[mb_][0], bfr[NH][nb_][0], *a_, 0, 0, 0); \
        *a_ = __builtin_amdgcn_mfma_f32_16x16x32_bf16(afr[mb_][1], bfr[NH][nb_][1], *a_, 0, 0, 0); \
      } } while (0)

// one K-tile: reads pipelined under MFMA via counted lgkm; 1 bar + 1 vmcnt.
#define GU_TILE(BB, STAGE_BODY) do { \
    STAGE_BODY; \
    GU_READA(BB, 0); \
    GU_READB(BB, 0); \
    GU_READB(BB, 1); \
    GU_LGK(4);   /* A0+B0 done; B1 may be outstanding */ \
    __builtin_amdgcn_s_setprio(1); GU_MFMAQ(0, 0); __builtin_amdgcn_s_setprio(0); \
    GU_LGK(0);   /* B1 done */ \
    __builtin_amdgcn_s_setprio(1); GU_MFMAQ(0, 1); __builtin_amdgcn_s_setprio(0); \
    GU_READA(BB, 1);  /* afr free; A1 reads overlap next MFMAs via skew */ \
    GU_LGK(0);   /* A1 done */ \
    __builtin_amdgcn_s_setprio(1); GU_MFMAQ(1, 1); GU_MFMAQ(1, 0); __builtin_amdgcn_s_setprio(0); \
    GU_VMC0();   /* retire this tile's stage burst (issued one tile ago) */ \
    GU_BAR(); \
  } while (0)

__global__ __launch_bounds__(512, 2) void mlp_gateup256_kernel(
    const bf16* __restrict__ A, const bf16* __restrict__ Bc,
    bf16* __restrict__ out, int M, int Ncat, int K)
{
  (void)M;
  __shared__ __align__(16) char smem[131072];
  const int tid  = threadIdx.x;
  const int wave = tid >> 6, lane = tid & 63;
  const int quad = lane >> 4, l16 = lane & 15;
  const int wr = wave >> 2, wc = wave & 3;
  const int bm = blockIdx.y << 8, bn = blockIdx.x << 8;
  const int KT = K >> 6;

  const int koff0 = (quad * 16) ^ ((l16 & 7) << 4);
  const int koff1 = koff0 ^ 64;
  const int wroff = wr * 16384;
  const int bhoff = (wc >> 1) * 16384;
  const int brow0 = (wc & 1) * 64 + l16;

  const int srow = lane >> 3;
  const int scol = ((lane & 7) ^ srow) << 3;
  const bf16* srcp[8]; int dstoff[8];
  #pragma unroll
  for (int op = 0; op < 2; ++op)
    #pragma unroll
    for (int h = 0; h < 2; ++h)
      #pragma unroll
      for (int g = 0; g < 2; ++g) {
        const int j = op * 4 + h * 2 + g;
        const int grow = (op ? bn : bm) + h * 128 + g * 64 + wave * 8 + srow;
        srcp[j] = (op ? Bc : A) + (long)grow * K + scol;
        dstoff[j] = op * 32768 + h * 16384 + g * 8192 + wave * 1024;
      }

  f32x4 acc[8][4] = {};
  bf16x8 afr[4][2];
  bf16x8 bfr[2][2][2];

  // prologue: tile 0 -> buf0, drain, barrier
  GU_STAGE(0, 0);
  GU_VMC0();
  GU_BAR();

  #pragma unroll 1
  for (int t = 0; t < KT; t += 2) {
    // tile t in buf0; stage t+1 -> buf1 (buf1's reads retired at prev tile-end bar)
    GU_TILE(0,     GU_STAGE(t + 1, 65536));
    // tile t+1 in buf1; stage t+2 -> buf0 (buf0 reads retired at bar above)
    GU_TILE(65536, if (t + 2 < KT) GU_STAGE(t + 2, 0));
  }

  // epilogue: fragment pair (nb even = gate, nb odd = up) -> silu(g)*u
  const long NO = Ncat >> 1;
  const int orow0 = bm + wr * 128 + (quad << 2);
  const int ocol  = (bn >> 1) + wc * 32 + l16;
  #pragma unroll
  for (int ma = 0; ma < 8; ++ma)
    #pragma unroll
    for (int nh = 0; nh < 2; ++nh)
      #pragma unroll
      for (int r = 0; r < 4; ++r) {
        const float g = acc[ma][nh * 2][r];
        const float u = acc[ma][nh * 2 + 1][r];
        out[(long)(orow0 + ma * 16 + r) * NO + ocol + nh * 16] =
            f2b(g / (1.0f + __expf(-g)) * u);
      }
}

// ---------- RoPE + layout ----------
__global__ __launch_bounds__(256) void rope_kernel(
    const bf16* __restrict__ qkv, bf16* __restrict__ Q,
    bf16* __restrict__ K, bf16* __restrict__ VT)
{
  const int t = blockIdx.x, b = blockIdx.y;
  const bf16* row = qkv + (long)(b * T_ + t) * QKVN_;
  const float tf = (float)t;
  for (int idx = threadIdx.x; idx < NH_ * HD_; idx += 256) {
    const int head = idx >> 7, hd = idx & 127;
    const float v = b2f(row[idx]);
    float o;
    if (hd < 64) {
      const int j = hd & 31;
      const float ang = tf * expf(-(float)j * 0.28782313662425574f);
      const float sn = sinf(ang), cs = cosf(ang);
      o = (hd < 32) ? (v * cs - b2f(row[idx + 32]) * sn)
                    : (v * cs + b2f(row[idx - 32]) * sn);
    } else o = v;
    Q[((long)(b * NH_ + head) * T_ + t) * HD_ + hd] = f2b(o);
  }
  for (int idx = threadIdx.x; idx < NKV_ * HD_; idx += 256) {
    const int kv = idx >> 7, hd = idx & 127;
    const float v = b2f(row[NH_ * HD_ + idx]);
    float o;
    if (hd < 64) {
      const int j = hd & 31;
      const float ang = tf * expf(-(float)j * 0.28782313662425574f);
      const float sn = sinf(ang), cs = cosf(ang);
      o = (hd < 32) ? (v * cs - b2f(row[NH_ * HD_ + idx + 32]) * sn)
                    : (v * cs + b2f(row[NH_ * HD_ + idx - 32]) * sn);
    } else o = v;
    K[((long)(b * NKV_ + kv) * T_ + t) * HD_ + hd] = f2b(o);
  }
  for (int idx = threadIdx.x; idx < NKV_ * HD_; idx += 256) {
    const int kv = idx >> 7, vd = idx & 127;
    VT[((long)(b * NKV_ + kv) * HD_ + vd) * T_ + t] = row[(NH_ + NKV_) * HD_ + idx];
  }
}

// ---------- Flash attention ----------
__global__ __launch_bounds__(256) void attn_kernel(
    const bf16* __restrict__ Q, const bf16* __restrict__ Kg,
    const bf16* __restrict__ VTg, const float* __restrict__ sink,
    bf16* __restrict__ attnb)
{
  __shared__ __align__(16) bf16 Qs[64 * 136];
  __shared__ __align__(16) bf16 Ks[64 * 136];
  __shared__ __align__(16) bf16 Vs[128 * 72];
  __shared__ __align__(16) bf16 Ps[64 * 72];

  const int qt = blockIdx.x;
  const int bh = blockIdx.y;
  const int b = bh >> 4, h = bh & 15;
  const int kvh = h >> 2;
  const int t0 = qt * 64;
  const int tid = threadIdx.x;
  const int wave = tid >> 6, lane = tid & 63;
  const int quad = lane >> 4, l16 = lane & 15;

  const bf16* Qp = Q + ((long)(b * NH_ + h) * T_ + t0) * HD_;
  #pragma unroll
  for (int c = tid; c < 1024; c += 256) {
    const int r = c >> 4, cc = (c & 15) << 3;
    *(uint4*)&Qs[r * 136 + cc] = *(const uint4*)&Qp[r * HD_ + cc];
  }

  float m_i[4], l_i[4];
  const float sb = sink[h];
  #pragma unroll
  for (int r = 0; r < 4; ++r) { m_i[r] = sb; l_i[r] = 1.0f; }
  f32x4 Oacc[8] = {};

  const int st_lo = (qt > 16) ? (qt - 16) : 0;
  for (int st = st_lo; st <= qt; ++st) {
    const int s0 = st * 64;
    __syncthreads();
    const bf16* Kp = Kg + ((long)(b * NKV_ + kvh) * T_ + s0) * HD_;
    #pragma unroll
    for (int c = tid; c < 1024; c += 256) {
      const int r = c >> 4, cc = (c & 15) << 3;
      *(uint4*)&Ks[r * 136 + cc] = *(const uint4*)&Kp[r * HD_ + cc];
    }
    const bf16* Vp = VTg + (long)(b * NKV_ + kvh) * HD_ * T_ + s0;
    #pragma unroll
    for (int c = tid; c < 1024; c += 256) {
      const int r = c >> 3, cc = (c & 7) << 3;
      *(uint4*)&Vs[r * 72 + cc] = *(const uint4*)&Vp[(long)r * T_ + cc];
    }
    __syncthreads();

    f32x4 sacc[4] = {};
    #pragma unroll
    for (int kb = 0; kb < 4; ++kb) {
      const bf16x8 aq = *(const bf16x8*)&Qs[(wave * 16 + l16) * 136 + kb * 32 + quad * 8];
      #pragma unroll
      for (int nb = 0; nb < 4; ++nb) {
        const bf16x8 bk = *(const bf16x8*)&Ks[(nb * 16 + l16) * 136 + kb * 32 + quad * 8];
        sacc[nb] = __builtin_amdgcn_mfma_f32_16x16x32_bf16(aq, bk, sacc[nb], 0, 0, 0);
      }
    }

    float sv[4][4];
    float rmax[4] = {-INFINITY, -INFINITY, -INFINITY, -INFINITY};
    const int colb = s0 + l16;
    const int rowb = t0 + wave * 16 + quad * 4;
    #pragma unroll
    for (int nb = 0; nb < 4; ++nb)
      #pragma unroll
      for (int r = 0; r < 4; ++r) {
        float v = sacc[nb][r] * 0.08838834764831845f;
        const int s = colb + nb * 16, tq = rowb + r;
        if (s > tq || s < tq - (WIN_ - 1)) v = -INFINITY;
        sv[nb][r] = v;
        rmax[r] = fmaxf(rmax[r], v);
      }
    #pragma unroll
    for (int r = 0; r < 4; ++r)
      #pragma unroll
      for (int off = 1; off < 16; off <<= 1)
        rmax[r] = fmaxf(rmax[r], __shfl_xor(rmax[r], off, 64));
    float alpha[4], rsum[4];
    #pragma unroll
    for (int r = 0; r < 4; ++r) {
      const float mn = fmaxf(m_i[r], rmax[r]);
      alpha[r] = __expf(m_i[r] - mn);
      m_i[r] = mn;
      rsum[r] = 0.0f;
    }
    #pragma unroll
    for (int nb = 0; nb < 4; ++nb)
      #pragma unroll
      for (int r = 0; r < 4; ++r) {
        const float p = __expf(sv[nb][r] - m_i[r]);
        rsum[r] += p;
        Ps[(wave * 16 + quad * 4 + r) * 72 + nb * 16 + l16] = f2b(p);
      }
    #pragma unroll
    for (int r = 0; r < 4; ++r) {
      #pragma unroll
      for (int off = 1; off < 16; off <<= 1)
        rsum[r] += __shfl_xor(rsum[r], off, 64);
      l_i[r] = l_i[r] * alpha[r] + rsum[r];
    }
    #pragma unroll
    for (int nb = 0; nb < 8; ++nb)
      #pragma unroll
      for (int r = 0; r < 4; ++r)
        Oacc[nb][r] *= alpha[r];
    __syncthreads();

    #pragma unroll
    for (int ks = 0; ks < 2; ++ks) {
      const bf16x8 ap = *(const bf16x8*)&Ps[(wave * 16 + l16) * 72 + ks * 32 + quad * 8];
      #pragma unroll
      for (int nb = 0; nb < 8; ++nb) {
        const bf16x8 bv = *(const bf16x8*)&Vs[(nb * 16 + l16) * 72 + ks * 32 + quad * 8];
        Oacc[nb] = __builtin_amdgcn_mfma_f32_16x16x32_bf16(ap, bv, Oacc[nb], 0, 0, 0);
      }
    }
  }

  float rcp[4];
  #pragma unroll
  for (int r = 0; r < 4; ++r) rcp[r] = 1.0f / l_i[r];
  bf16* outp = attnb + ((long)(b * T_ + t0 + wave * 16 + quad * 4)) * EMB_ + h * HD_ + l16;
  #pragma unroll
  for (int nb = 0; nb < 8; ++nb)
    #pragma unroll
    for (int r = 0; r < 4; ++r)
      outp[(long)r * EMB_ + nb * 16] = f2b(Oacc[nb][r] * rcp[r]);
}

extern "C" void kernel_launch(void* const* d_in, const int* in_sizes, int n_in,
                              void* d_out, int out_size, void* d_ws, size_t ws_size,
                              hipStream_t stream)
{
  (void)in_sizes; (void)n_in; (void)out_size; (void)ws_size;
  const float* x    = (const float*)d_in[0];
  const float* wq   = (const float*)d_in[2];
  const float* wk   = (const float*)d_in[3];
  const float* wv   = (const float*)d_in[4];
  const float* wo   = (const float*)d_in[5];
  const float* sink = (const float*)d_in[6];
  const float* gw   = (const float*)d_in[7];
  const float* uw   = (const float*)d_in[8];
  const float* dw   = (const float*)d_in[9];
  const float* n1   = (const float*)d_in[10];
  const float* n2   = (const float*)d_in[11];

  char* base = (char*)d_ws;
  bf16*  hbuf  = (bf16*)base;                                   // 16,777,216
  char*  R1    = base + (size_t)16777216;                       // 67,108,864
  char*  R2    = R1   + (size_t)67108864;                       // 33,554,432
  bf16*  mact  = (bf16*)(R2 + (size_t)33554432);                // 67,108,864

  bf16* qkv   = (bf16*)R1;
  bf16* Qb    = (bf16*)(R1 + 25165824);
  bf16* Kb    = (bf16*)(R1 + 41943040);
  bf16* VTb   = (bf16*)(R1 + 46137344);
  bf16* attnb = (bf16*)R1;
  bf16* wqkvT = (bf16*)R2;
  bf16* woT   = (bf16*)(R2 + 12582912);
  bf16* Bcat  = (bf16*)R1;            // 16384 x 2048 bf16 (gate/up interleaved)
  bf16* downT = (bf16*)R2;
  float* x1   = (float*)d_out;

  const dim3 tb(32, 8);
  // ---- phase A: attention ----
  transpose_kernel<<<dim3( 64,  64), tb, 0, stream>>>(wq, wqkvT,                      EMB_, EMB_, 1, 0);
  transpose_kernel<<<dim3( 16,  64), tb, 0, stream>>>(wk, wqkvT + (size_t)2048*EMB_,  EMB_, 512, 1, 0);
  transpose_kernel<<<dim3( 16,  64), tb, 0, stream>>>(wv, wqkvT + (size_t)2560*EMB_,  EMB_, 512, 1, 0);
  transpose_kernel<<<dim3( 64,  64), tb, 0, stream>>>(wo, woT,                        EMB_, EMB_, 1, 0);

  rmsnorm_kernel<<<BT_, 256, 0, stream>>>(x, n1, hbuf);
  gemm256_kernel<0><<<dim3(QKVN_/256, BT_/128), 512, 0, stream>>>(hbuf, wqkvT, qkv, nullptr, BT_, QKVN_, EMB_);
  rope_kernel<<<dim3(T_, B_), 256, 0, stream>>>(qkv, Qb, Kb, VTb);
  attn_kernel<<<dim3(T_/64, B_*NH_), 256, 0, stream>>>(Qb, Kb, VTb, sink, attnb);
  gemm256_kernel<1><<<dim3(EMB_/256, BT_/128), 512, 0, stream>>>(attnb, woT, x1, x, BT_, EMB_, EMB_);

  // ---- phase B: MLP ----
  rmsnorm_kernel<<<BT_, 256, 0, stream>>>(x1, n2, hbuf);
  transpose_kernel<<<dim3(256,  64), tb, 0, stream>>>(gw, Bcat, EMB_, MLPD_, 2, 0);
  transpose_kernel<<<dim3(256,  64), tb, 0, stream>>>(uw, Bcat, EMB_, MLPD_, 2, 1);
  mlp_gateup256_kernel<<<dim3((2*MLPD_)/256, BT_/256), 512, 0, stream>>>(hbuf, Bcat, mact, BT_, 2*MLPD_, EMB_);
  transpose_kernel<<<dim3( 64, 256), tb, 0, stream>>>(dw, downT, MLPD_, EMB_, 1, 0);
  gemm256_kernel<1><<<dim3(EMB_/256, BT_/128), 512, 0, stream>>>(mact, downT, (float*)d_out, x1, BT_, EMB_, MLPD_);
}